// Round 4
// baseline (320.446 us; speedup 1.0000x reference)
//
#include <hip/hip_runtime.h>
#include <stdint.h>

typedef float v4f __attribute__((ext_vector_type(4)));
typedef short v8s __attribute__((ext_vector_type(8)));

#define SZ_BHTD 8388608   // B*H*T*DH
#define SZ_HTD  131072    // T*DH

#define GL2LDS(g, l) __builtin_amdgcn_global_load_lds( \
    (const __attribute__((address_space(1))) void*)(g), \
    (__attribute__((address_space(3))) void*)(l), 16, 0, 0)

// raw barrier: no vmcnt drain, but a compiler-level memory fence on both sides
#define BAR() do{ asm volatile("" ::: "memory"); __builtin_amdgcn_s_barrier(); asm volatile("" ::: "memory"); }while(0)

// Inline-asm LDS read: opaque to the compiler's waitcnt pass, so NO auto vmcnt
// drain is inserted for the global_load_lds producers (the counted vmcnt in the
// main loop is the only VMEM wait). Requires manual lgkmcnt(0)+sched_barrier(0)
// before consuming (rule #18).
typedef __attribute__((address_space(3))) const uint16_t* lds_cu16p;
__device__ __forceinline__ v8s LDSRD(const uint16_t* p){
  v8s r;
  asm volatile("ds_read_b128 %0, %1" : "=&v"(r) : "v"((lds_cu16p)p));
  return r;
}

__device__ __forceinline__ uint16_t f2bf(float f){
  uint32_t u = __float_as_uint(f);
  u += 0x7fffu + ((u >> 16) & 1u);
  return (uint16_t)(u >> 16);
}
__device__ __forceinline__ float bf2f(uint16_t v){
  return __uint_as_float(((uint32_t)v) << 16);
}

// Fused conversions: blocks [0,8192): x fp32->bf16; [8192,8960): W transpose->bf16
__global__ __launch_bounds__(256) void k_conv(const float* __restrict__ x,
                                              const float* __restrict__ Wq, const float* __restrict__ Wk,
                                              const float* __restrict__ Wv,
                                              uint16_t* __restrict__ xb, uint16_t* __restrict__ wt){
  if (blockIdx.x < 8192){
    int i = blockIdx.x*256 + threadIdx.x;
    const float4 v = ((const float4*)x)[i];
    ushort4 o; o.x = f2bf(v.x); o.y = f2bf(v.y); o.z = f2bf(v.z); o.w = f2bf(v.w);
    ((ushort4*)xb)[i] = o;
    return;
  }
  __shared__ float t[64][65];
  const int blk2 = blockIdx.x - 8192;          // [0,768)
  const int z = blk2 >> 8, y = (blk2 >> 4) & 15, xx = blk2 & 15;
  const float* W = z==0 ? Wq : (z==1 ? Wk : Wv);
  int n0 = xx*64, k0 = y*64;
  for (int idx = threadIdx.x; idx < 4096; idx += 256){
    int r = idx >> 6, c = idx & 63;
    t[r][c] = W[(k0+r)*1024 + n0 + c];
  }
  __syncthreads();
  for (int idx = threadIdx.x; idx < 4096; idx += 256){
    int r = idx >> 6, c = idx & 63;   // r: local n, c: local k
    wt[(size_t)(z*1024 + n0 + r)*1024 + k0 + c] = f2bf(t[c][r]);
  }
}

// QKV = Xb @ Wt^T.
// 256x256 tile, BK=64, 8 waves (2Mx4N), per-wave 128x64 output.
// 4 quadrant phases per K-tile, 12 asm ds_read_b128 + 16 MFMA per phase,
// raw s_barrier + counted vmcnt (never 0 in steady state), setprio around MFMA.
// LDS double-buffered (128 KiB). XOR-swizzled LDS via pre-swizzled global source.
// launch_bounds: 512 with NO min-blocks arg. Round 2's (512,2) forced a 128-VGPR
// cap (2 co-resident blocks can't exist anyway: 128 KiB LDS = 1 block/CU) and
// spilled ~70 registers -> scratch traffic + MfmaUtil 14%. The working set is
// ~200 VGPR (acc 128 + 12 asm ds_read temps 48 + addressing); 256 cap fits it.
#define NT 16
__global__ __launch_bounds__(512) void k_gemm(const uint16_t* __restrict__ Xb, const uint16_t* __restrict__ Wt,
                                              uint16_t* __restrict__ qkv){
  __shared__ uint16_t As[2][256*64];
  __shared__ uint16_t Bs[2][256*64];
  const int tid = threadIdx.x;
  const int lane = tid & 63, w = tid >> 6;     // w: 0..7
  const int quad = lane >> 4, l16 = lane & 15;
  const int wm = w >> 2, wn = w & 3;           // 2M x 4N wave grid
  const int bm = blockIdx.x, bn = blockIdx.y;
  const uint16_t* Ag = Xb + (size_t)(bm*256)*1024;
  const uint16_t* Bg = Wt + (size_t)(bn*256)*1024;
  const int rA = lane >> 3;                    // row within 8-row chunk (staging)
  const int ce = (((lane & 7) ^ rA) * 8);      // pre-swizzled 16B source chunk
  const int xr = l16 & 7;                      // reader-side XOR key
  const int c0 = (quad ^ xr) * 8;              // kk=0 chunk
  const int c1 = ((quad + 4) ^ xr) * 8;        // kk=32 chunk
  const int abase = (wm*128 + l16)*64;
  const int bbase = (wn*64 + l16)*64;
  v4f acc[8][4] = {};

#define STAGE(kt, buf) do{ \
    const int _k0 = (kt)*64; \
    _Pragma("unroll") \
    for (int _j = 0; _j < 4; ++_j){ \
      const int _row = _j*64 + w*8; \
      GL2LDS(Ag + (size_t)(_row + rA)*1024 + _k0 + ce, &As[buf][_row*64]); \
      GL2LDS(Bg + (size_t)(_row + rA)*1024 + _k0 + ce, &Bs[buf][_row*64]); \
    } \
  }while(0)

  // prologue: tiles 0 and 1 in flight; wait tile 0 (8 newest stay outstanding)
  STAGE(0, 0);
  STAGE(1, 1);
  asm volatile("s_waitcnt vmcnt(8)" ::: "memory");
  BAR();

  #pragma unroll 2
  for (int t = 0; t < NT; ++t){
    const int cur = t & 1;
    const uint16_t* Asb = As[cur];
    const uint16_t* Bsb = Bs[cur];
    #pragma unroll
    for (int q = 0; q < 4; ++q){
      const int mh = q >> 1, nh = q & 1;
      v8s a0[4], a1[4], b0[2], b1[2];
      #pragma unroll
      for (int im = 0; im < 4; ++im){
        const int ro = abase + (mh*64 + im*16)*64;
        a0[im] = LDSRD(&Asb[ro + c0]);
        a1[im] = LDSRD(&Asb[ro + c1]);
      }
      #pragma unroll
      for (int in = 0; in < 2; ++in){
        const int ro = bbase + (nh*32 + in*16)*64;
        b0[in] = LDSRD(&Bsb[ro + c0]);
        b1[in] = LDSRD(&Bsb[ro + c1]);
      }
      BAR();
      asm volatile("s_waitcnt lgkmcnt(0)" ::: "memory");
      __builtin_amdgcn_sched_barrier(0);
      __builtin_amdgcn_s_setprio(1);
      #pragma unroll
      for (int im = 0; im < 4; ++im){
        #pragma unroll
        for (int in = 0; in < 2; ++in){
          acc[mh*4+im][nh*2+in] = __builtin_amdgcn_mfma_f32_16x16x32_bf16(a0[im], b0[in], acc[mh*4+im][nh*2+in], 0, 0, 0);
          acc[mh*4+im][nh*2+in] = __builtin_amdgcn_mfma_f32_16x16x32_bf16(a1[im], b1[in], acc[mh*4+im][nh*2+in], 0, 0, 0);
        }
      }
      __builtin_amdgcn_s_setprio(0);
      BAR();
    }
    // group end: buf[cur] fully consumed by all waves (phase-3 barriers above)
    if (t < NT-2) STAGE(t+2, cur);
    if (t < NT-1){
      if (t < NT-2){ asm volatile("s_waitcnt vmcnt(8)" ::: "memory"); }
      else         { asm volatile("s_waitcnt vmcnt(0)" ::: "memory"); }
      BAR();
    }
  }
#undef STAGE

  #pragma unroll
  for (int mi = 0; mi < 8; ++mi){
    #pragma unroll
    for (int ni = 0; ni < 4; ++ni){
      int n = bn*256 + wn*64 + ni*16 + l16;
      int which = n >> 10, cch = n & 1023;
      int hh = cch >> 6, dd = cch & 63;
      #pragma unroll
      for (int r = 0; r < 4; ++r){
        int m = bm*256 + wm*128 + mi*16 + quad*4 + r;
        int b = m >> 11, tt = m & 2047;
        qkv[(size_t)which*SZ_BHTD + (size_t)((b*16 + hh)*2048 + tt)*64 + dd] = f2bf(acc[mi][ni][r]);
      }
    }
  }
}

// Per (b,h,chunk): UT[d][e]=sum_s g^{63-s}K[s][e]V[s][d]; CK[d][e]=sum_s K[s][d]V[s][e];
// head[e] = qbar . pkv with qbar[d]=sum_j g^j Q[j][d].
__global__ __launch_bounds__(256) void k_pre(const uint16_t* __restrict__ qkv, const float* __restrict__ pkv,
                                             uint16_t* __restrict__ UT, uint16_t* __restrict__ ckp,
                                             float* __restrict__ headv){
  __shared__ uint16_t KTb[64*72];   // [d][s] = K[s][d]
  __shared__ uint16_t VTb[64*72];   // [e][s] = V[s][e]
  __shared__ uint16_t VTw[64*72];   // [d][s] = g^{63-s} V[s][d]
  __shared__ float tab[65];
  __shared__ float qbar[64];
  const int tid = threadIdx.x, blk = blockIdx.x;
  const int bh = blk >> 5, c = blk & 31, h = bh & 15;
  const int lane = tid & 63, w = tid >> 6;
  const int quad = lane >> 4, l16 = lane & 15;
  const float g = 1.0f - exp2f(-(float)(5 + h));
  if (tid <= 64) tab[tid] = powf(g, (float)tid);
  const uint16_t* Qg = qkv + (size_t)bh*SZ_HTD + c*4096;
  const uint16_t* Kg = Qg + SZ_BHTD;
  const uint16_t* Vg = Qg + 2*(size_t)SZ_BHTD;
  const float* Pg = pkv + h*4096;
  __syncthreads();
  #pragma unroll
  for (int it = 0; it < 16; ++it){
    int idx = it*256 + tid;            // idx = s*64 + d
    int s = idx >> 6, d = idx & 63;
    uint16_t kv = Kg[idx], vv = Vg[idx];
    KTb[d*72 + s] = kv;
    VTb[d*72 + s] = vv;
    VTw[d*72 + s] = f2bf(tab[63 - s]*bf2f(vv));
  }
  if (tid < 64){
    float acc = 0.f;
    for (int j = 0; j < 64; ++j) acc = fmaf(tab[j], bf2f(Qg[j*64 + tid]), acc);
    qbar[tid] = acc;
  }
  __syncthreads();
  const int ar = (w*16 + l16)*72 + quad*8;
  v8s aK0 = *(v8s*)&KTb[ar], aK1 = *(v8s*)&KTb[ar + 32];
  v8s aW0 = *(v8s*)&VTw[ar], aW1 = *(v8s*)&VTw[ar + 32];
  v4f accC[4] = {}, accU[4] = {};
  #pragma unroll
  for (int ni = 0; ni < 4; ++ni){
    const int br = (ni*16 + l16)*72 + quad*8;
    v8s bV0 = *(v8s*)&VTb[br], bV1 = *(v8s*)&VTb[br + 32];
    v8s bK0 = *(v8s*)&KTb[br], bK1 = *(v8s*)&KTb[br + 32];
    accC[ni] = __builtin_amdgcn_mfma_f32_16x16x32_bf16(aK0, bV0, accC[ni], 0, 0, 0);
    accC[ni] = __builtin_amdgcn_mfma_f32_16x16x32_bf16(aK1, bV1, accC[ni], 0, 0, 0);
    accU[ni] = __builtin_amdgcn_mfma_f32_16x16x32_bf16(aW0, bK0, accU[ni], 0, 0, 0);
    accU[ni] = __builtin_amdgcn_mfma_f32_16x16x32_bf16(aW1, bK1, accU[ni], 0, 0, 0);
  }
  const size_t ob = (size_t)blk*4096;
  #pragma unroll
  for (int ni = 0; ni < 4; ++ni){
    int e = ni*16 + l16;
    #pragma unroll
    for (int r = 0; r < 4; ++r){
      int d = w*16 + quad*4 + r;
      ckp[ob + d*64 + e] = f2bf(accC[ni][r]);
      UT[ob + d*64 + e]  = f2bf(accU[ni][r]);
    }
  }
  if (tid < 64){
    float acc = 0.f;
    for (int dd = 0; dd < 64; ++dd) acc = fmaf(qbar[dd], Pg[dd*64 + tid], acc);
    headv[(size_t)blk*64 + tid] = acc;
  }
}

// Merged scans. Blocks [0,256): forward state scan S; blocks [256,272): backward tail scan.
__global__ __launch_bounds__(256) void k_scan(const uint16_t* __restrict__ UT, uint16_t* __restrict__ S,
                                              const float* __restrict__ headv, float* __restrict__ tailv){
  if (blockIdx.x < 256){
    const int bh = blockIdx.x >> 2, part = blockIdx.x & 3, h = bh & 15;
    const float g = 1.0f - exp2f(-(float)(5 + h));
    const float g64 = powf(g, 64.0f);
    const int off = part*1024 + threadIdx.x*4;
    float st0=0.f, st1=0.f, st2=0.f, st3=0.f;
    for (int c = 0; c < 32; ++c){
      const size_t base = ((size_t)bh*32 + c)*4096 + off;
      ushort4 u = *(const ushort4*)&UT[base];
      ushort4 o; o.x=f2bf(st0); o.y=f2bf(st1); o.z=f2bf(st2); o.w=f2bf(st3);
      *(ushort4*)&S[base] = o;
      st0 = fmaf(g64, st0, bf2f(u.x)); st1 = fmaf(g64, st1, bf2f(u.y));
      st2 = fmaf(g64, st2, bf2f(u.z)); st3 = fmaf(g64, st3, bf2f(u.w));
    }
    return;
  }
  const int lin = (blockIdx.x - 256)*256 + threadIdx.x;   // 4096 = B*H*DH
  const int bh = lin >> 6, e = lin & 63, h = bh & 15;
  const float g = 1.0f - exp2f(-(float)(5 + h));
  const float g64 = powf(g, 64.0f);
  float R = 0.0f;
  for (int c = 31; c >= 0; --c){
    const size_t o = ((size_t)bh*32 + c)*64 + e;
    tailv[o] = R;
    R = fmaf(g64, R, headv[o]);
  }
}

// Fused main: P=QK^T, pp=Q pkv^T, inter=Q S^T, intra=P' V, cx = M pp^T (all MFMA);
// ret (bf16) = intra + g^{i+1} inter + cx + g^{64-i} tail; partial GroupNorm stats.
__global__ __launch_bounds__(256) void k_main(const uint16_t* __restrict__ qkv, const uint16_t* __restrict__ Sg_,
                                              const float* __restrict__ pkv, const float* __restrict__ tailv,
                                              uint16_t* __restrict__ ret, float2* __restrict__ pb){
  __shared__ uint16_t Qb[64*72];    // Q rows [i][d]
  __shared__ uint16_t Kb[64*72];    // K rows [j][d] -> P' rows [i][s]
  __shared__ uint16_t VTb[64*72];   // [d][s] = V[s][d]
  __shared__ uint16_t B2[64*72];    // [e][d] = pkv[d][e] -> ppT [e][j]
  __shared__ uint16_t Sb[64*72];    // S rows [d][e]
  __shared__ float tab[65];
  __shared__ float ps[8];
  const int tid = threadIdx.x, blk = blockIdx.x;
  const int bh = blk >> 5, c = blk & 31, h = bh & 15;
  const int lane = tid & 63, w = tid >> 6;
  const int quad = lane >> 4, l16 = lane & 15;
  const float g = 1.0f - exp2f(-(float)(5 + h));
  if (tid <= 64) tab[tid] = powf(g, (float)tid);
  const uint16_t* Qg = qkv + (size_t)bh*SZ_HTD + c*4096;
  const uint16_t* Kg = Qg + SZ_BHTD;
  const uint16_t* Vg = Qg + 2*(size_t)SZ_BHTD;
  const uint16_t* Sgp = Sg_ + (size_t)blk*4096;
  const float* Pg = pkv + h*4096;
  #pragma unroll
  for (int v = 0; v < 2; ++v){
    int idx = (tid*2 + v)*8;
    int r = idx >> 6, cc = idx & 63;
    *(uint4*)&Qb[r*72 + cc] = *(const uint4*)&Qg[idx];
    *(uint4*)&Kb[r*72 + cc] = *(const uint4*)&Kg[idx];
    *(uint4*)&Sb[r*72 + cc] = *(const uint4*)&Sgp[idx];
  }
  #pragma unroll
  for (int it = 0; it < 16; ++it){
    int idx = it*256 + tid;          // Vg: idx = s*64+d ; pkv: idx = d*64+e
    int r = idx >> 6, cc = idx & 63;
    VTb[cc*72 + r] = Vg[idx];        // VTb[d][s]
    B2[cc*72 + r] = f2bf(Pg[idx]);   // B2[e][d]
  }
  __syncthreads();
  const int ar = (w*16 + l16)*72 + quad*8;
  v8s aQ0 = *(v8s*)&Qb[ar], aQ1 = *(v8s*)&Qb[ar + 32];
  v4f accP[4] = {}, accPP[4] = {}, accIT[4] = {};
  #pragma unroll
  for (int ni = 0; ni < 4; ++ni){
    const int br = (ni*16 + l16)*72 + quad*8;
    v8s b0 = *(v8s*)&Kb[br], b1 = *(v8s*)&Kb[br + 32];
    accP[ni] = __builtin_amdgcn_mfma_f32_16x16x32_bf16(aQ0, b0, accP[ni], 0, 0, 0);
    accP[ni] = __builtin_amdgcn_mfma_f32_16x16x32_bf16(aQ1, b1, accP[ni], 0, 0, 0);
    v8s c0 = *(v8s*)&B2[br], c1 = *(v8s*)&B2[br + 32];
    accPP[ni] = __builtin_amdgcn_mfma_f32_16x16x32_bf16(aQ0, c0, accPP[ni], 0, 0, 0);
    accPP[ni] = __builtin_amdgcn_mfma_f32_16x16x32_bf16(aQ1, c1, accPP[ni], 0, 0, 0);
    v8s d0 = *(v8s*)&Sb[br], d1 = *(v8s*)&Sb[br + 32];
    accIT[ni] = __builtin_amdgcn_mfma_f32_16x16x32_bf16(aQ0, d0, accIT[ni], 0, 0, 0);
    accIT[ni] = __builtin_amdgcn_mfma_f32_16x16x32_bf16(aQ1, d1, accIT[ni], 0, 0, 0);
  }
  __syncthreads();   // all reads of Kb/B2 complete
  #pragma unroll
  for (int ni = 0; ni < 4; ++ni){
    #pragma unroll
    for (int r = 0; r < 4; ++r){
      int i = w*16 + quad*4 + r;     // row (time)
      int j = ni*16 + l16;           // col
      Kb[i*72 + j] = f2bf((i >= j) ? accP[ni][r]*tab[i - j] : 0.0f);   // P'
      B2[j*72 + i] = f2bf(accPP[ni][r]);                               // ppT[e][i]
    }
  }
  __syncthreads();
  v8s aP0 = *(v8s*)&Kb[ar], aP1 = *(v8s*)&Kb[ar + 32];
  v8s aM0, aM1;
  {
    int i = w*16 + l16;
    #pragma unroll
    for (int u = 0; u < 8; ++u){
      int j0 = quad*8 + u, j1 = 32 + quad*8 + u;
      aM0[u] = (short)f2bf((j0 >= i) ? tab[j0 - i] : 0.0f);
      aM1[u] = (short)f2bf((j1 >= i) ? tab[j1 - i] : 0.0f);
    }
  }
  v4f accI[4] = {}, accX[4] = {};
  #pragma unroll
  for (int ni = 0; ni < 4; ++ni){
    const int br = (ni*16 + l16)*72 + quad*8;
    v8s b0 = *(v8s*)&VTb[br], b1 = *(v8s*)&VTb[br + 32];
    accI[ni] = __builtin_amdgcn_mfma_f32_16x16x32_bf16(aP0, b0, accI[ni], 0, 0, 0);
    accI[ni] = __builtin_amdgcn_mfma_f32_16x16x32_bf16(aP1, b1, accI[ni], 0, 0, 0);
    v8s e0 = *(v8s*)&B2[br], e1 = *(v8s*)&B2[br + 32];
    accX[ni] = __builtin_amdgcn_mfma_f32_16x16x32_bf16(aM0, e0, accX[ni], 0, 0, 0);
    accX[ni] = __builtin_amdgcn_mfma_f32_16x16x32_bf16(aM1, e1, accX[ni], 0, 0, 0);
  }
  const size_t rbase = (size_t)bh*2048 + (size_t)c*64;
  float s1 = 0.f, s2 = 0.f;
  #pragma unroll
  for (int ni = 0; ni < 4; ++ni){
    int d = ni*16 + l16;
    float tl = tailv[(size_t)blk*64 + d];
    #pragma unroll
    for (int r = 0; r < 4; ++r){
      int i = w*16 + quad*4 + r;
      float v = accI[ni][r] + tab[i + 1]*accIT[ni][r] + accX[ni][r] + tab[64 - i]*tl;
      ret[(rbase + i)*64 + d] = f2bf(v);
      s1 += v; s2 += v*v;
    }
  }
  #pragma unroll
  for (int off = 32; off > 0; off >>= 1){
    s1 += __shfl_down(s1, off);
    s2 += __shfl_down(s2, off);
  }
  if (lane == 0){ ps[w*2] = s1; ps[w*2+1] = s2; }
  __syncthreads();
  if (tid == 0){
    float2 o; o.x = ps[0] + ps[2] + ps[4] + ps[6];
    o.y = ps[1] + ps[3] + ps[5] + ps[7];
    pb[blk] = o;
  }
}

// reduce 512 per-block partials per batch -> stats
__global__ __launch_bounds__(256) void k_stats(const float2* __restrict__ pb, float* __restrict__ stats){
  __shared__ float ps[8];
  const int b = blockIdx.x;
  float s = 0.0f, s2 = 0.0f;
  for (int i = threadIdx.x; i < 512; i += 256){
    const float2 p = pb[(size_t)b*512 + i];
    s += p.x; s2 += p.y;
  }
  #pragma unroll
  for (int off = 32; off > 0; off >>= 1){
    s  += __shfl_down(s, off);
    s2 += __shfl_down(s2, off);
  }
  const int wv = threadIdx.x >> 6;
  if ((threadIdx.x & 63) == 0){ ps[wv*2] = s; ps[wv*2+1] = s2; }
  __syncthreads();
  if (threadIdx.x == 0){
    stats[b*2]   = ps[0] + ps[2] + ps[4] + ps[6];
    stats[b*2+1] = ps[1] + ps[3] + ps[5] + ps[7];
  }
}

// GroupNorm apply + layout to [B,T,NE]
__global__ __launch_bounds__(256) void k_norm(const uint16_t* __restrict__ ret, const float* __restrict__ stats,
                                              const float* __restrict__ gw, const float* __restrict__ gb,
                                              float* __restrict__ out){
  const int o = (blockIdx.x*256 + threadIdx.x)*4;
  const int b = o >> 21, t = (o >> 10) & 2047, cch = o & 1023;
  const int h = cch >> 6, d = cch & 63;
  const float inv = 1.0f/2097152.0f;
  const float mu = stats[b*2]*inv;
  const float var = stats[b*2+1]*inv - mu*mu;
  const float rs = rsqrtf(var + 1e-5f);
  const float w = gw[h]*rs, bb = gb[h];
  const ushort4 v = *(const ushort4*)&ret[((size_t)(b*16 + h)*2048 + t)*64 + d];
  float4 r;
  r.x = (bf2f(v.x) - mu)*w + bb; r.y = (bf2f(v.y) - mu)*w + bb;
  r.z = (bf2f(v.z) - mu)*w + bb; r.w = (bf2f(v.w) - mu)*w + bb;
  *(float4*)&out[o] = r;
}

// current_kv = gamma*past_kv + mean_b K^T V  (reduce 128 partials)
__global__ __launch_bounds__(64) void k_ckb(const float* __restrict__ pkv, const uint16_t* __restrict__ ckp,
                                            float* __restrict__ out2){
  const int lin = blockIdx.x*64 + threadIdx.x;  // 16384
  const int i = lin*4;
  const int h = i >> 12, de = i & 4095;
  const float g = 1.0f - exp2f(-(float)(5 + h));
  float acc[4] = {0.0f, 0.0f, 0.0f, 0.0f};
  for (int b = 0; b < 4; ++b){
    const uint16_t* base = ckp + ((size_t)(b*16 + h)*32)*4096 + de;
    for (int c = 0; c < 32; ++c){
      #pragma unroll
      for (int u = 0; u < 4; ++u) acc[u] += bf2f(base[(size_t)c*4096 + u]);
    }
  }
  #pragma unroll
  for (int u = 0; u < 4; ++u)
    out2[i + u] = fmaf(g, pkv[i + u], 0.25f*acc[u]);
}

extern "C" void kernel_launch(void* const* d_in, const int* in_sizes, int n_in,
                              void* d_out, int out_size, void* d_ws, size_t ws_size,
                              hipStream_t stream){
  const float* x   = (const float*)d_in[0];
  const float* pkv = (const float*)d_in[1];
  const float* Wq  = (const float*)d_in[2];
  const float* Wk  = (const float*)d_in[3];
  const float* Wv  = (const float*)d_in[4];
  const float* gnw = (const float*)d_in[5];
  const float* gnb = (const float*)d_in[6];
  float* out  = (float*)d_out;
  float* out2 = out + 8388608;

  char* ws = (char*)d_ws;
  size_t off = 0;
  float*    stats = (float*)(ws + off);    off += 256;
  float2*   pb    = (float2*)(ws + off);   off += (size_t)8192*8;
  uint16_t* Xb    = (uint16_t*)(ws + off); off += (size_t)8388608*2;
  uint16_t* Wt    = (uint16_t*)(ws + off); off += (size_t)3145728*2;
  uint16_t* QKV   = (uint16_t*)(ws + off); off += (size_t)3*8388608*2;
  uint16_t* ret   = (uint16_t*)(ws + off); off += (size_t)8388608*2;
  uint16_t* UT    = (uint16_t*)(ws + off); off += (size_t)8388608*2;
  uint16_t* S     = (uint16_t*)(ws + off); off += (size_t)8388608*2;
  uint16_t* CKp   = (uint16_t*)(ws + off); off += (size_t)8388608*2;
  float*    headv = (float*)(ws + off);    off += (size_t)131072*4;
  float*    tailv = (float*)(ws + off);    off += (size_t)131072*4;

  k_conv<<<8960, 256, 0, stream>>>(x, Wq, Wk, Wv, Xb, Wt);
  k_gemm<<<dim3(32, 12), 512, 0, stream>>>(Xb, Wt, QKV);
  k_pre<<<2048, 256, 0, stream>>>(QKV, pkv, UT, CKp, headv);
  k_scan<<<272, 256, 0, stream>>>(UT, S, headv, tailv);
  k_main<<<2048, 256, 0, stream>>>(QKV, S, pkv, tailv, ret, pb);
  k_stats<<<4, 256, 0, stream>>>(pb, stats);
  k_norm<<<8192, 256, 0, stream>>>(ret, stats, gnw, gnb, out);
  k_ckb<<<256, 64, 0, stream>>>(pkv, CKp, out2);
}

// Round 5
// 254.435 us; speedup vs baseline: 1.2594x; 1.2594x over previous
//
#include <hip/hip_runtime.h>
#include <stdint.h>

typedef float v4f __attribute__((ext_vector_type(4)));
typedef short v8s __attribute__((ext_vector_type(8)));

#define SZ_BHTD 8388608   // B*H*T*DH
#define SZ_HTD  131072    // T*DH

#define GL2LDS(g, l) __builtin_amdgcn_global_load_lds( \
    (const __attribute__((address_space(1))) void*)(g), \
    (__attribute__((address_space(3))) void*)(l), 16, 0, 0)

__device__ __forceinline__ uint16_t f2bf(float f){
  uint32_t u = __float_as_uint(f);
  u += 0x7fffu + ((u >> 16) & 1u);
  return (uint16_t)(u >> 16);
}
__device__ __forceinline__ float bf2f(uint16_t v){
  return __uint_as_float(((uint32_t)v) << 16);
}

// Fused conversions: blocks [0,8192): x fp32->bf16; [8192,8960): W transpose->bf16
__global__ __launch_bounds__(256) void k_conv(const float* __restrict__ x,
                                              const float* __restrict__ Wq, const float* __restrict__ Wk,
                                              const float* __restrict__ Wv,
                                              uint16_t* __restrict__ xb, uint16_t* __restrict__ wt){
  if (blockIdx.x < 8192){
    int i = blockIdx.x*256 + threadIdx.x;
    const float4 v = ((const float4*)x)[i];
    ushort4 o; o.x = f2bf(v.x); o.y = f2bf(v.y); o.z = f2bf(v.z); o.w = f2bf(v.w);
    ((ushort4*)xb)[i] = o;
    return;
  }
  __shared__ float t[64][65];
  const int blk2 = blockIdx.x - 8192;          // [0,768)
  const int z = blk2 >> 8, y = (blk2 >> 4) & 15, xx = blk2 & 15;
  const float* W = z==0 ? Wq : (z==1 ? Wk : Wv);
  int n0 = xx*64, k0 = y*64;
  for (int idx = threadIdx.x; idx < 4096; idx += 256){
    int r = idx >> 6, c = idx & 63;
    t[r][c] = W[(k0+r)*1024 + n0 + c];
  }
  __syncthreads();
  for (int idx = threadIdx.x; idx < 4096; idx += 256){
    int r = idx >> 6, c = idx & 63;   // r: local n, c: local k
    wt[(size_t)(z*1024 + n0 + r)*1024 + k0 + c] = f2bf(t[c][r]);
  }
}

// QKV = Xb @ Wt^T. 128x128 tile, BK=64, global_load_lds width 16, XOR-swizzled LDS.
// LDS(r, c16) holds global(r, c16 ^ (r&7)); reader XORs chunk with (l16&7).
// m97-structure kernel, harness-verified 63.7 us / 805 TF. The 8-phase 256^2
// transplant was abandoned after 3 structural failures: (R1) compiler vmcnt
// drains before plain LDS reads; (R2) spills under the (512,2) 128-VGPR cap;
// (R4) 512-thr block => 2 waves/SIMD => 256-reg hard cap, 128+128 arch/AGPR
// split spills regardless of launch_bounds. This structure is at its
// documented ~900 TF ceiling; do not re-attempt without the m201 source.
__global__ __launch_bounds__(256) void k_gemm(const uint16_t* __restrict__ Xb, const uint16_t* __restrict__ Wt,
                                              uint16_t* __restrict__ qkv){
  __shared__ uint16_t As[128*64];
  __shared__ uint16_t Bs[128*64];
  const int tid = threadIdx.x;
  const int lane = tid & 63, w = tid >> 6;
  const int quad = lane >> 4, l16 = lane & 15;
  const int wm = (w >> 1)*64, wn = (w & 1)*64;
  const int bm = blockIdx.x, bn = blockIdx.y;
  v4f acc[4][4] = {};
  const uint16_t* Ag = Xb + (size_t)(bm*128)*1024;
  const uint16_t* Bg = Wt + (size_t)(bn*128)*1024;
  const int rA = lane >> 3;                     // 0..7 row within 8-row chunk
  const int ce = (((lane & 7) ^ rA) * 8);       // swizzled 16B column chunk (elements)
  const int xr = l16 & 7;                       // reader-side XOR key
  for (int k0 = 0; k0 < 1024; k0 += 64){
    #pragma unroll
    for (int j = 0; j < 4; ++j){
      const int cA = w*4 + j;                   // covers rows [cA*8, cA*8+8)
      const int r = cA*8 + rA;
      GL2LDS(Ag + (size_t)r*1024 + k0 + ce, As + cA*512);
      GL2LDS(Bg + (size_t)r*1024 + k0 + ce, Bs + cA*512);
    }
    __syncthreads();
    #pragma unroll
    for (int kk = 0; kk < 64; kk += 32){
      const int ch = ((quad + (kk >> 3)) ^ xr) * 8;   // kk=0 -> quad, kk=32 -> quad+4, then XOR
      v8s a[4], b[4];
      #pragma unroll
      for (int u = 0; u < 4; ++u) a[u] = *(v8s*)&As[(wm + u*16 + l16)*64 + ch];
      #pragma unroll
      for (int u = 0; u < 4; ++u) b[u] = *(v8s*)&Bs[(wn + u*16 + l16)*64 + ch];
      #pragma unroll
      for (int mi = 0; mi < 4; ++mi)
        #pragma unroll
        for (int ni = 0; ni < 4; ++ni)
          acc[mi][ni] = __builtin_amdgcn_mfma_f32_16x16x32_bf16(a[mi], b[ni], acc[mi][ni], 0, 0, 0);
    }
    __syncthreads();
  }
  #pragma unroll
  for (int mi = 0; mi < 4; ++mi){
    #pragma unroll
    for (int ni = 0; ni < 4; ++ni){
      int n = bn*128 + wn + ni*16 + l16;
      int which = n >> 10, cch = n & 1023;
      int hh = cch >> 6, dd = cch & 63;
      #pragma unroll
      for (int r = 0; r < 4; ++r){
        int m = bm*128 + wm + mi*16 + quad*4 + r;
        int b = m >> 11, t = m & 2047;
        qkv[(size_t)which*SZ_BHTD + (size_t)((b*16 + hh)*2048 + t)*64 + dd] = f2bf(acc[mi][ni][r]);
      }
    }
  }
}

// Per (b,h,chunk): UT[d][e]=sum_s g^{63-s}K[s][e]V[s][d]; CK[d][e]=sum_s K[s][d]V[s][e];
// head[e] = qbar . pkv with qbar[d]=sum_j g^j Q[j][d].
// qbar/headv GEMVs parallelized across all 256 threads (4 partials + LDS reduce)
// instead of 64-thread 64-iteration serial loops.
__global__ __launch_bounds__(256) void k_pre(const uint16_t* __restrict__ qkv, const float* __restrict__ pkv,
                                             uint16_t* __restrict__ UT, uint16_t* __restrict__ ckp,
                                             float* __restrict__ headv){
  __shared__ uint16_t KTb[64*72];   // [d][s] = K[s][d]
  __shared__ uint16_t VTb[64*72];   // [e][s] = V[s][e]
  __shared__ uint16_t VTw[64*72];   // [d][s] = g^{63-s} V[s][d]
  __shared__ float tab[65];
  __shared__ float qbar[64];
  __shared__ float part4[4][64];    // partial-reduce buffer (qbar, then headv)
  const int tid = threadIdx.x, blk = blockIdx.x;
  const int bh = blk >> 5, c = blk & 31, h = bh & 15;
  const int lane = tid & 63, w = tid >> 6;
  const int quad = lane >> 4, l16 = lane & 15;
  const float g = 1.0f - exp2f(-(float)(5 + h));
  if (tid <= 64) tab[tid] = powf(g, (float)tid);
  const uint16_t* Qg = qkv + (size_t)bh*SZ_HTD + c*4096;
  const uint16_t* Kg = Qg + SZ_BHTD;
  const uint16_t* Vg = Qg + 2*(size_t)SZ_BHTD;
  const float* Pg = pkv + h*4096;
  __syncthreads();
  #pragma unroll
  for (int it = 0; it < 16; ++it){
    int idx = it*256 + tid;            // idx = s*64 + d
    int s = idx >> 6, d = idx & 63;
    uint16_t kv = Kg[idx], vv = Vg[idx];
    KTb[d*72 + s] = kv;
    VTb[d*72 + s] = vv;
    VTw[d*72 + s] = f2bf(tab[63 - s]*bf2f(vv));
  }
  {  // qbar partials: thread (w, lane) sums j in [w*16, w*16+16) for d=lane
    float acc = 0.f;
    #pragma unroll
    for (int jj = 0; jj < 16; ++jj){
      int j = w*16 + jj;
      acc = fmaf(tab[j], bf2f(Qg[j*64 + lane]), acc);
    }
    part4[w][lane] = acc;
  }
  __syncthreads();
  if (tid < 64) qbar[tid] = part4[0][tid] + part4[1][tid] + part4[2][tid] + part4[3][tid];
  const int ar = (w*16 + l16)*72 + quad*8;
  v8s aK0 = *(v8s*)&KTb[ar], aK1 = *(v8s*)&KTb[ar + 32];
  v8s aW0 = *(v8s*)&VTw[ar], aW1 = *(v8s*)&VTw[ar + 32];
  v4f accC[4] = {}, accU[4] = {};
  #pragma unroll
  for (int ni = 0; ni < 4; ++ni){
    const int br = (ni*16 + l16)*72 + quad*8;
    v8s bV0 = *(v8s*)&VTb[br], bV1 = *(v8s*)&VTb[br + 32];
    v8s bK0 = *(v8s*)&KTb[br], bK1 = *(v8s*)&KTb[br + 32];
    accC[ni] = __builtin_amdgcn_mfma_f32_16x16x32_bf16(aK0, bV0, accC[ni], 0, 0, 0);
    accC[ni] = __builtin_amdgcn_mfma_f32_16x16x32_bf16(aK1, bV1, accC[ni], 0, 0, 0);
    accU[ni] = __builtin_amdgcn_mfma_f32_16x16x32_bf16(aW0, bK0, accU[ni], 0, 0, 0);
    accU[ni] = __builtin_amdgcn_mfma_f32_16x16x32_bf16(aW1, bK1, accU[ni], 0, 0, 0);
  }
  const size_t ob = (size_t)blk*4096;
  #pragma unroll
  for (int ni = 0; ni < 4; ++ni){
    int e = ni*16 + l16;
    #pragma unroll
    for (int r = 0; r < 4; ++r){
      int d = w*16 + quad*4 + r;
      ckp[ob + d*64 + e] = f2bf(accC[ni][r]);
      UT[ob + d*64 + e]  = f2bf(accU[ni][r]);
    }
  }
  __syncthreads();   // qbar visible to all; part4 free for reuse
  {  // headv partials: thread (w, lane) sums d in [w*16, w*16+16) for e=lane
    float acc = 0.f;
    #pragma unroll
    for (int dd = 0; dd < 16; ++dd){
      int d = w*16 + dd;
      acc = fmaf(qbar[d], Pg[d*64 + lane], acc);
    }
    part4[w][lane] = acc;
  }
  __syncthreads();
  if (tid < 64)
    headv[(size_t)blk*64 + tid] = part4[0][tid] + part4[1][tid] + part4[2][tid] + part4[3][tid];
}

// Merged scans. Blocks [0,1024): forward state scan S (scalar per thread: 4096
// waves = 16/CU for latency hiding; was 1024 waves). Blocks [1024,1040): tail scan.
__global__ __launch_bounds__(256) void k_scan(const uint16_t* __restrict__ UT, uint16_t* __restrict__ S,
                                              const float* __restrict__ headv, float* __restrict__ tailv){
  if (blockIdx.x < 1024){
    const int lin = blockIdx.x*256 + threadIdx.x;   // 262144 = 64 bh * 4096 elems
    const int bh = lin >> 12, off = lin & 4095, h = bh & 15;
    const float g = 1.0f - exp2f(-(float)(5 + h));
    const float g64 = powf(g, 64.0f);
    float st = 0.f;
    for (int c = 0; c < 32; ++c){
      const size_t base = ((size_t)(bh*32 + c))*4096 + off;
      uint16_t u = UT[base];
      S[base] = f2bf(st);
      st = fmaf(g64, st, bf2f(u));
    }
    return;
  }
  const int lin = (blockIdx.x - 1024)*256 + threadIdx.x;   // 4096 = B*H*DH
  const int bh = lin >> 6, e = lin & 63, h = bh & 15;
  const float g = 1.0f - exp2f(-(float)(5 + h));
  const float g64 = powf(g, 64.0f);
  float R = 0.0f;
  for (int c = 31; c >= 0; --c){
    const size_t o = ((size_t)bh*32 + c)*64 + e;
    tailv[o] = R;
    R = fmaf(g64, R, headv[o]);
  }
}

// Fused main: P=QK^T, pp=Q pkv^T, inter=Q S^T, intra=P' V, cx = M pp^T (all MFMA);
// ret (bf16) = intra + g^{i+1} inter + cx + g^{64-i} tail; partial GroupNorm stats.
__global__ __launch_bounds__(256) void k_main(const uint16_t* __restrict__ qkv, const uint16_t* __restrict__ Sg_,
                                              const float* __restrict__ pkv, const float* __restrict__ tailv,
                                              uint16_t* __restrict__ ret, float2* __restrict__ pb){
  __shared__ uint16_t Qb[64*72];    // Q rows [i][d]
  __shared__ uint16_t Kb[64*72];    // K rows [j][d] -> P' rows [i][s]
  __shared__ uint16_t VTb[64*72];   // [d][s] = V[s][d]
  __shared__ uint16_t B2[64*72];    // [e][d] = pkv[d][e] -> ppT [e][j]
  __shared__ uint16_t Sb[64*72];    // S rows [d][e]
  __shared__ float tab[65];
  __shared__ float ps[8];
  const int tid = threadIdx.x, blk = blockIdx.x;
  const int bh = blk >> 5, c = blk & 31, h = bh & 15;
  const int lane = tid & 63, w = tid >> 6;
  const int quad = lane >> 4, l16 = lane & 15;
  const float g = 1.0f - exp2f(-(float)(5 + h));
  if (tid <= 64) tab[tid] = powf(g, (float)tid);
  const uint16_t* Qg = qkv + (size_t)bh*SZ_HTD + c*4096;
  const uint16_t* Kg = Qg + SZ_BHTD;
  const uint16_t* Vg = Qg + 2*(size_t)SZ_BHTD;
  const uint16_t* Sgp = Sg_ + (size_t)blk*4096;
  const float* Pg = pkv + h*4096;
  #pragma unroll
  for (int v = 0; v < 2; ++v){
    int idx = (tid*2 + v)*8;
    int r = idx >> 6, cc = idx & 63;
    *(uint4*)&Qb[r*72 + cc] = *(const uint4*)&Qg[idx];
    *(uint4*)&Kb[r*72 + cc] = *(const uint4*)&Kg[idx];
    *(uint4*)&Sb[r*72 + cc] = *(const uint4*)&Sgp[idx];
  }
  #pragma unroll
  for (int it = 0; it < 16; ++it){
    int idx = it*256 + tid;          // Vg: idx = s*64+d ; pkv: idx = d*64+e
    int r = idx >> 6, cc = idx & 63;
    VTb[cc*72 + r] = Vg[idx];        // VTb[d][s]
    B2[cc*72 + r] = f2bf(Pg[idx]);   // B2[e][d]
  }
  __syncthreads();
  const int ar = (w*16 + l16)*72 + quad*8;
  v8s aQ0 = *(v8s*)&Qb[ar], aQ1 = *(v8s*)&Qb[ar + 32];
  v4f accP[4] = {}, accPP[4] = {}, accIT[4] = {};
  #pragma unroll
  for (int ni = 0; ni < 4; ++ni){
    const int br = (ni*16 + l16)*72 + quad*8;
    v8s b0 = *(v8s*)&Kb[br], b1 = *(v8s*)&Kb[br + 32];
    accP[ni] = __builtin_amdgcn_mfma_f32_16x16x32_bf16(aQ0, b0, accP[ni], 0, 0, 0);
    accP[ni] = __builtin_amdgcn_mfma_f32_16x16x32_bf16(aQ1, b1, accP[ni], 0, 0, 0);
    v8s c0 = *(v8s*)&B2[br], c1 = *(v8s*)&B2[br + 32];
    accPP[ni] = __builtin_amdgcn_mfma_f32_16x16x32_bf16(aQ0, c0, accPP[ni], 0, 0, 0);
    accPP[ni] = __builtin_amdgcn_mfma_f32_16x16x32_bf16(aQ1, c1, accPP[ni], 0, 0, 0);
    v8s d0 = *(v8s*)&Sb[br], d1 = *(v8s*)&Sb[br + 32];
    accIT[ni] = __builtin_amdgcn_mfma_f32_16x16x32_bf16(aQ0, d0, accIT[ni], 0, 0, 0);
    accIT[ni] = __builtin_amdgcn_mfma_f32_16x16x32_bf16(aQ1, d1, accIT[ni], 0, 0, 0);
  }
  __syncthreads();   // all reads of Kb/B2 complete
  #pragma unroll
  for (int ni = 0; ni < 4; ++ni){
    #pragma unroll
    for (int r = 0; r < 4; ++r){
      int i = w*16 + quad*4 + r;     // row (time)
      int j = ni*16 + l16;           // col
      Kb[i*72 + j] = f2bf((i >= j) ? accP[ni][r]*tab[i - j] : 0.0f);   // P'
      B2[j*72 + i] = f2bf(accPP[ni][r]);                               // ppT[e][i]
    }
  }
  __syncthreads();
  v8s aP0 = *(v8s*)&Kb[ar], aP1 = *(v8s*)&Kb[ar + 32];
  v8s aM0, aM1;
  {
    int i = w*16 + l16;
    #pragma unroll
    for (int u = 0; u < 8; ++u){
      int j0 = quad*8 + u, j1 = 32 + quad*8 + u;
      aM0[u] = (short)f2bf((j0 >= i) ? tab[j0 - i] : 0.0f);
      aM1[u] = (short)f2bf((j1 >= i) ? tab[j1 - i] : 0.0f);
    }
  }
  v4f accI[4] = {}, accX[4] = {};
  #pragma unroll
  for (int ni = 0; ni < 4; ++ni){
    const int br = (ni*16 + l16)*72 + quad*8;
    v8s b0 = *(v8s*)&VTb[br], b1 = *(v8s*)&VTb[br + 32];
    accI[ni] = __builtin_amdgcn_mfma_f32_16x16x32_bf16(aP0, b0, accI[ni], 0, 0, 0);
    accI[ni] = __builtin_amdgcn_mfma_f32_16x16x32_bf16(aP1, b1, accI[ni], 0, 0, 0);
    v8s e0 = *(v8s*)&B2[br], e1 = *(v8s*)&B2[br + 32];
    accX[ni] = __builtin_amdgcn_mfma_f32_16x16x32_bf16(aM0, e0, accX[ni], 0, 0, 0);
    accX[ni] = __builtin_amdgcn_mfma_f32_16x16x32_bf16(aM1, e1, accX[ni], 0, 0, 0);
  }
  const size_t rbase = (size_t)bh*2048 + (size_t)c*64;
  float s1 = 0.f, s2 = 0.f;
  #pragma unroll
  for (int ni = 0; ni < 4; ++ni){
    int d = ni*16 + l16;
    float tl = tailv[(size_t)blk*64 + d];
    #pragma unroll
    for (int r = 0; r < 4; ++r){
      int i = w*16 + quad*4 + r;
      float v = accI[ni][r] + tab[i + 1]*accIT[ni][r] + accX[ni][r] + tab[64 - i]*tl;
      ret[(rbase + i)*64 + d] = f2bf(v);
      s1 += v; s2 += v*v;
    }
  }
  #pragma unroll
  for (int off = 32; off > 0; off >>= 1){
    s1 += __shfl_down(s1, off);
    s2 += __shfl_down(s2, off);
  }
  if (lane == 0){ ps[w*2] = s1; ps[w*2+1] = s2; }
  __syncthreads();
  if (tid == 0){
    float2 o; o.x = ps[0] + ps[2] + ps[4] + ps[6];
    o.y = ps[1] + ps[3] + ps[5] + ps[7];
    pb[blk] = o;
  }
}

// Merged: blocks [0,256): current_kv reduce; blocks [256,260): GroupNorm stats
// reduce (512 per-batch partials -> stats). One launch instead of two.
__global__ __launch_bounds__(64) void k_ckbs(const float* __restrict__ pkv, const uint16_t* __restrict__ ckp,
                                             const float2* __restrict__ pb, float* __restrict__ out2,
                                             float* __restrict__ stats){
  if (blockIdx.x < 256){
    const int lin = blockIdx.x*64 + threadIdx.x;  // 16384
    const int i = lin*4;
    const int h = i >> 12, de = i & 4095;
    const float g = 1.0f - exp2f(-(float)(5 + h));
    float acc[4] = {0.0f, 0.0f, 0.0f, 0.0f};
    for (int b = 0; b < 4; ++b){
      const uint16_t* base = ckp + ((size_t)(b*16 + h)*32)*4096 + de;
      for (int c = 0; c < 32; ++c){
        #pragma unroll
        for (int u = 0; u < 4; ++u) acc[u] += bf2f(base[(size_t)c*4096 + u]);
      }
    }
    #pragma unroll
    for (int u = 0; u < 4; ++u)
      out2[i + u] = fmaf(g, pkv[i + u], 0.25f*acc[u]);
    return;
  }
  const int b = blockIdx.x - 256;
  float s = 0.0f, s2 = 0.0f;
  for (int i = threadIdx.x; i < 512; i += 64){
    const float2 p = pb[(size_t)b*512 + i];
    s += p.x; s2 += p.y;
  }
  #pragma unroll
  for (int off = 32; off > 0; off >>= 1){
    s  += __shfl_down(s, off);
    s2 += __shfl_down(s2, off);
  }
  if (threadIdx.x == 0){
    stats[b*2]   = s;
    stats[b*2+1] = s2;
  }
}

// GroupNorm apply + layout to [B,T,NE]
__global__ __launch_bounds__(256) void k_norm(const uint16_t* __restrict__ ret, const float* __restrict__ stats,
                                              const float* __restrict__ gw, const float* __restrict__ gb,
                                              float* __restrict__ out){
  const int o = (blockIdx.x*256 + threadIdx.x)*4;
  const int b = o >> 21, t = (o >> 10) & 2047, cch = o & 1023;
  const int h = cch >> 6, d = cch & 63;
  const float inv = 1.0f/2097152.0f;
  const float mu = stats[b*2]*inv;
  const float var = stats[b*2+1]*inv - mu*mu;
  const float rs = rsqrtf(var + 1e-5f);
  const float w = gw[h]*rs, bb = gb[h];
  const ushort4 v = *(const ushort4*)&ret[((size_t)(b*16 + h)*2048 + t)*64 + d];
  float4 r;
  r.x = (bf2f(v.x) - mu)*w + bb; r.y = (bf2f(v.y) - mu)*w + bb;
  r.z = (bf2f(v.z) - mu)*w + bb; r.w = (bf2f(v.w) - mu)*w + bb;
  *(float4*)&out[o] = r;
}

extern "C" void kernel_launch(void* const* d_in, const int* in_sizes, int n_in,
                              void* d_out, int out_size, void* d_ws, size_t ws_size,
                              hipStream_t stream){
  const float* x   = (const float*)d_in[0];
  const float* pkv = (const float*)d_in[1];
  const float* Wq  = (const float*)d_in[2];
  const float* Wk  = (const float*)d_in[3];
  const float* Wv  = (const float*)d_in[4];
  const float* gnw = (const float*)d_in[5];
  const float* gnb = (const float*)d_in[6];
  float* out  = (float*)d_out;
  float* out2 = out + 8388608;

  char* ws = (char*)d_ws;
  size_t off = 0;
  float*    stats = (float*)(ws + off);    off += 256;
  float2*   pb    = (float2*)(ws + off);   off += (size_t)8192*8;
  uint16_t* Xb    = (uint16_t*)(ws + off); off += (size_t)8388608*2;
  uint16_t* Wt    = (uint16_t*)(ws + off); off += (size_t)3145728*2;
  uint16_t* QKV   = (uint16_t*)(ws + off); off += (size_t)3*8388608*2;
  uint16_t* ret   = (uint16_t*)(ws + off); off += (size_t)8388608*2;
  uint16_t* UT    = (uint16_t*)(ws + off); off += (size_t)8388608*2;
  uint16_t* S     = (uint16_t*)(ws + off); off += (size_t)8388608*2;
  uint16_t* CKp   = (uint16_t*)(ws + off); off += (size_t)8388608*2;
  float*    headv = (float*)(ws + off);    off += (size_t)131072*4;
  float*    tailv = (float*)(ws + off);    off += (size_t)131072*4;

  k_conv<<<8960, 256, 0, stream>>>(x, Wq, Wk, Wv, Xb, Wt);
  k_gemm<<<dim3(64, 24), 256, 0, stream>>>(Xb, Wt, QKV);
  k_pre<<<2048, 256, 0, stream>>>(QKV, pkv, UT, CKp, headv);
  k_scan<<<1040, 256, 0, stream>>>(UT, S, headv, tailv);
  k_main<<<2048, 256, 0, stream>>>(QKV, S, pkv, tailv, ret, pb);
  k_ckbs<<<260, 64, 0, stream>>>(pkv, CKp, pb, out2, stats);
  k_norm<<<8192, 256, 0, stream>>>(ret, stats, gnw, gnb, out);
}

// Round 6
// 233.339 us; speedup vs baseline: 1.3733x; 1.0904x over previous
//
#include <hip/hip_runtime.h>
#include <stdint.h>

typedef float v4f __attribute__((ext_vector_type(4)));
typedef short v8s __attribute__((ext_vector_type(8)));

#define SZ_BHTD 8388608   // B*H*T*DH
#define SZ_HTD  131072    // T*DH

#define GL2LDS(g, l) __builtin_amdgcn_global_load_lds( \
    (const __attribute__((address_space(1))) void*)(g), \
    (__attribute__((address_space(3))) void*)(l), 16, 0, 0)

__device__ __forceinline__ uint16_t f2bf(float f){
  uint32_t u = __float_as_uint(f);
  u += 0x7fffu + ((u >> 16) & 1u);
  return (uint16_t)(u >> 16);
}
__device__ __forceinline__ float bf2f(uint16_t v){
  return __uint_as_float(((uint32_t)v) << 16);
}

// Fused conversions: blocks [0,8192): x fp32->bf16; [8192,8960): W transpose->bf16
__global__ __launch_bounds__(256) void k_conv(const float* __restrict__ x,
                                              const float* __restrict__ Wq, const float* __restrict__ Wk,
                                              const float* __restrict__ Wv,
                                              uint16_t* __restrict__ xb, uint16_t* __restrict__ wt){
  if (blockIdx.x < 8192){
    int i = blockIdx.x*256 + threadIdx.x;
    const float4 v = ((const float4*)x)[i];
    ushort4 o; o.x = f2bf(v.x); o.y = f2bf(v.y); o.z = f2bf(v.z); o.w = f2bf(v.w);
    ((ushort4*)xb)[i] = o;
    return;
  }
  __shared__ float t[64][65];
  const int blk2 = blockIdx.x - 8192;          // [0,768)
  const int z = blk2 >> 8, y = (blk2 >> 4) & 15, xx = blk2 & 15;
  const float* W = z==0 ? Wq : (z==1 ? Wk : Wv);
  int n0 = xx*64, k0 = y*64;
  for (int idx = threadIdx.x; idx < 4096; idx += 256){
    int r = idx >> 6, c = idx & 63;
    t[r][c] = W[(k0+r)*1024 + n0 + c];
  }
  __syncthreads();
  for (int idx = threadIdx.x; idx < 4096; idx += 256){
    int r = idx >> 6, c = idx & 63;   // r: local n, c: local k
    wt[(size_t)(z*1024 + n0 + r)*1024 + k0 + c] = f2bf(t[c][r]);
  }
}

// QKV = Xb @ Wt^T. 128x128 tile, BK=64, global_load_lds width 16, XOR-swizzled LDS.
// m97-structure kernel, harness-verified ~64 us / 805 TF (its documented ceiling).
// 8-phase transplant abandoned after 3 structural failures (R1/R2/R4); do not retry.
__global__ __launch_bounds__(256) void k_gemm(const uint16_t* __restrict__ Xb, const uint16_t* __restrict__ Wt,
                                              uint16_t* __restrict__ qkv){
  __shared__ uint16_t As[128*64];
  __shared__ uint16_t Bs[128*64];
  const int tid = threadIdx.x;
  const int lane = tid & 63, w = tid >> 6;
  const int quad = lane >> 4, l16 = lane & 15;
  const int wm = (w >> 1)*64, wn = (w & 1)*64;
  const int bm = blockIdx.x, bn = blockIdx.y;
  v4f acc[4][4] = {};
  const uint16_t* Ag = Xb + (size_t)(bm*128)*1024;
  const uint16_t* Bg = Wt + (size_t)(bn*128)*1024;
  const int rA = lane >> 3;                     // 0..7 row within 8-row chunk
  const int ce = (((lane & 7) ^ rA) * 8);       // swizzled 16B column chunk (elements)
  const int xr = l16 & 7;                       // reader-side XOR key
  for (int k0 = 0; k0 < 1024; k0 += 64){
    #pragma unroll
    for (int j = 0; j < 4; ++j){
      const int cA = w*4 + j;                   // covers rows [cA*8, cA*8+8)
      const int r = cA*8 + rA;
      GL2LDS(Ag + (size_t)r*1024 + k0 + ce, As + cA*512);
      GL2LDS(Bg + (size_t)r*1024 + k0 + ce, Bs + cA*512);
    }
    __syncthreads();
    #pragma unroll
    for (int kk = 0; kk < 64; kk += 32){
      const int ch = ((quad + (kk >> 3)) ^ xr) * 8;   // kk=0 -> quad, kk=32 -> quad+4, then XOR
      v8s a[4], b[4];
      #pragma unroll
      for (int u = 0; u < 4; ++u) a[u] = *(v8s*)&As[(wm + u*16 + l16)*64 + ch];
      #pragma unroll
      for (int u = 0; u < 4; ++u) b[u] = *(v8s*)&Bs[(wn + u*16 + l16)*64 + ch];
      #pragma unroll
      for (int mi = 0; mi < 4; ++mi)
        #pragma unroll
        for (int ni = 0; ni < 4; ++ni)
          acc[mi][ni] = __builtin_amdgcn_mfma_f32_16x16x32_bf16(a[mi], b[ni], acc[mi][ni], 0, 0, 0);
    }
    __syncthreads();
  }
  #pragma unroll
  for (int mi = 0; mi < 4; ++mi){
    #pragma unroll
    for (int ni = 0; ni < 4; ++ni){
      int n = bn*128 + wn + ni*16 + l16;
      int which = n >> 10, cch = n & 1023;
      int hh = cch >> 6, dd = cch & 63;
      #pragma unroll
      for (int r = 0; r < 4; ++r){
        int m = bm*128 + wm + mi*16 + quad*4 + r;
        int b = m >> 11, t = m & 2047;
        qkv[(size_t)which*SZ_BHTD + (size_t)((b*16 + hh)*2048 + t)*64 + dd] = f2bf(acc[mi][ni][r]);
      }
    }
  }
}

// Per (b,h,chunk): UT[d][e]=sum_s g^{63-s}K[s][e]V[s][d]; CK[d][e]=sum_s K[s][d]V[s][e];
// head[e] = qbar . pkv with qbar[d]=sum_j g^j Q[j][d].
__global__ __launch_bounds__(256) void k_pre(const uint16_t* __restrict__ qkv, const float* __restrict__ pkv,
                                             uint16_t* __restrict__ UT, uint16_t* __restrict__ ckp,
                                             float* __restrict__ headv){
  __shared__ uint16_t KTb[64*72];   // [d][s] = K[s][d]
  __shared__ uint16_t VTb[64*72];   // [e][s] = V[s][e]
  __shared__ uint16_t VTw[64*72];   // [d][s] = g^{63-s} V[s][d]
  __shared__ float tab[65];
  __shared__ float qbar[64];
  __shared__ float part4[4][64];    // partial-reduce buffer (qbar, then headv)
  const int tid = threadIdx.x, blk = blockIdx.x;
  const int bh = blk >> 5, c = blk & 31, h = bh & 15;
  const int lane = tid & 63, w = tid >> 6;
  const int quad = lane >> 4, l16 = lane & 15;
  const float g = 1.0f - exp2f(-(float)(5 + h));
  if (tid <= 64) tab[tid] = powf(g, (float)tid);
  const uint16_t* Qg = qkv + (size_t)bh*SZ_HTD + c*4096;
  const uint16_t* Kg = Qg + SZ_BHTD;
  const uint16_t* Vg = Qg + 2*(size_t)SZ_BHTD;
  const float* Pg = pkv + h*4096;
  __syncthreads();
  #pragma unroll
  for (int it = 0; it < 16; ++it){
    int idx = it*256 + tid;            // idx = s*64 + d
    int s = idx >> 6, d = idx & 63;
    uint16_t kv = Kg[idx], vv = Vg[idx];
    KTb[d*72 + s] = kv;
    VTb[d*72 + s] = vv;
    VTw[d*72 + s] = f2bf(tab[63 - s]*bf2f(vv));
  }
  {  // qbar partials: thread (w, lane) sums j in [w*16, w*16+16) for d=lane
    float acc = 0.f;
    #pragma unroll
    for (int jj = 0; jj < 16; ++jj){
      int j = w*16 + jj;
      acc = fmaf(tab[j], bf2f(Qg[j*64 + lane]), acc);
    }
    part4[w][lane] = acc;
  }
  __syncthreads();
  if (tid < 64) qbar[tid] = part4[0][tid] + part4[1][tid] + part4[2][tid] + part4[3][tid];
  const int ar = (w*16 + l16)*72 + quad*8;
  v8s aK0 = *(v8s*)&KTb[ar], aK1 = *(v8s*)&KTb[ar + 32];
  v8s aW0 = *(v8s*)&VTw[ar], aW1 = *(v8s*)&VTw[ar + 32];
  v4f accC[4] = {}, accU[4] = {};
  #pragma unroll
  for (int ni = 0; ni < 4; ++ni){
    const int br = (ni*16 + l16)*72 + quad*8;
    v8s bV0 = *(v8s*)&VTb[br], bV1 = *(v8s*)&VTb[br + 32];
    v8s bK0 = *(v8s*)&KTb[br], bK1 = *(v8s*)&KTb[br + 32];
    accC[ni] = __builtin_amdgcn_mfma_f32_16x16x32_bf16(aK0, bV0, accC[ni], 0, 0, 0);
    accC[ni] = __builtin_amdgcn_mfma_f32_16x16x32_bf16(aK1, bV1, accC[ni], 0, 0, 0);
    accU[ni] = __builtin_amdgcn_mfma_f32_16x16x32_bf16(aW0, bK0, accU[ni], 0, 0, 0);
    accU[ni] = __builtin_amdgcn_mfma_f32_16x16x32_bf16(aW1, bK1, accU[ni], 0, 0, 0);
  }
  const size_t ob = (size_t)blk*4096;
  #pragma unroll
  for (int ni = 0; ni < 4; ++ni){
    int e = ni*16 + l16;
    #pragma unroll
    for (int r = 0; r < 4; ++r){
      int d = w*16 + quad*4 + r;
      ckp[ob + d*64 + e] = f2bf(accC[ni][r]);
      UT[ob + d*64 + e]  = f2bf(accU[ni][r]);
    }
  }
  __syncthreads();   // qbar visible to all; part4 free for reuse
  {  // headv partials: thread (w, lane) sums d in [w*16, w*16+16) for e=lane
    float acc = 0.f;
    #pragma unroll
    for (int dd = 0; dd < 16; ++dd){
      int d = w*16 + dd;
      acc = fmaf(qbar[d], Pg[d*64 + lane], acc);
    }
    part4[w][lane] = acc;
  }
  __syncthreads();
  if (tid < 64)
    headv[(size_t)blk*64 + tid] = part4[0][tid] + part4[1][tid] + part4[2][tid] + part4[3][tid];
}

// Merged scans + current_kv reduce.
// Blocks [0,1024): forward state scan S. [1024,1040): backward tail scan.
// [1040,1104): current_kv = gamma*past_kv + mean_b K^T V (reads CKp, ready after
// k_pre) — moved here so its 16.8 MB read overlaps the scan instead of
// serializing between k_main and k_norm.
__global__ __launch_bounds__(256) void k_scan(const uint16_t* __restrict__ UT, uint16_t* __restrict__ S,
                                              const float* __restrict__ headv, float* __restrict__ tailv,
                                              const float* __restrict__ pkv, const uint16_t* __restrict__ ckp,
                                              float* __restrict__ out2){
  if (blockIdx.x < 1024){
    const int lin = blockIdx.x*256 + threadIdx.x;   // 262144 = 64 bh * 4096 elems
    const int bh = lin >> 12, off = lin & 4095, h = bh & 15;
    const float g = 1.0f - exp2f(-(float)(5 + h));
    const float g64 = powf(g, 64.0f);
    float st = 0.f;
    for (int c = 0; c < 32; ++c){
      const size_t base = ((size_t)(bh*32 + c))*4096 + off;
      uint16_t u = UT[base];
      S[base] = f2bf(st);
      st = fmaf(g64, st, bf2f(u));
    }
    return;
  }
  if (blockIdx.x < 1040){
    const int lin = (blockIdx.x - 1024)*256 + threadIdx.x;   // 4096 = B*H*DH
    const int bh = lin >> 6, e = lin & 63, h = bh & 15;
    const float g = 1.0f - exp2f(-(float)(5 + h));
    const float g64 = powf(g, 64.0f);
    float R = 0.0f;
    for (int c = 31; c >= 0; --c){
      const size_t o = ((size_t)bh*32 + c)*64 + e;
      tailv[o] = R;
      R = fmaf(g64, R, headv[o]);
    }
    return;
  }
  const int lin = (blockIdx.x - 1040)*256 + threadIdx.x;  // 16384
  const int i = lin*4;
  const int h = i >> 12, de = i & 4095;
  const float g = 1.0f - exp2f(-(float)(5 + h));
  float acc[4] = {0.0f, 0.0f, 0.0f, 0.0f};
  for (int b = 0; b < 4; ++b){
    const uint16_t* base = ckp + ((size_t)(b*16 + h)*32)*4096 + de;
    for (int c = 0; c < 32; ++c){
      #pragma unroll
      for (int u = 0; u < 4; ++u) acc[u] += bf2f(base[(size_t)c*4096 + u]);
    }
  }
  #pragma unroll
  for (int u = 0; u < 4; ++u)
    out2[i + u] = fmaf(g, pkv[i + u], 0.25f*acc[u]);
}

// Fused main: P=QK^T, pp=Q pkv^T, inter=Q S^T, intra=P' V, cx = M pp^T (all MFMA);
// ret (bf16) = intra + g^{i+1} inter + cx + g^{64-i} tail; partial GroupNorm stats.
// Qb and Sb LDS staging ELIMINATED: both were only read as row-major MFMA
// fragments (row = w*16+l16, k-chunk = quad), which is a direct 16B-aligned
// global v8s load. LDS 46.5 -> 27.7 KB => 5 blocks/CU (was 3, LDS-capped).
__global__ __launch_bounds__(256) void k_main(const uint16_t* __restrict__ qkv, const uint16_t* __restrict__ Sg_,
                                              const float* __restrict__ pkv, const float* __restrict__ tailv,
                                              uint16_t* __restrict__ ret, float2* __restrict__ pb){
  __shared__ uint16_t Kb[64*72];    // K rows [j][d] -> P' rows [i][s]
  __shared__ uint16_t VTb[64*72];   // [d][s] = V[s][d]
  __shared__ uint16_t B2[64*72];    // [e][d] = pkv[d][e] -> ppT [e][j]
  __shared__ float tab[65];
  __shared__ float ps[8];
  const int tid = threadIdx.x, blk = blockIdx.x;
  const int bh = blk >> 5, c = blk & 31, h = bh & 15;
  const int lane = tid & 63, w = tid >> 6;
  const int quad = lane >> 4, l16 = lane & 15;
  const float g = 1.0f - exp2f(-(float)(5 + h));
  if (tid <= 64) tab[tid] = powf(g, (float)tid);
  const uint16_t* Qg = qkv + (size_t)bh*SZ_HTD + c*4096;
  const uint16_t* Kg = Qg + SZ_BHTD;
  const uint16_t* Vg = Qg + 2*(size_t)SZ_BHTD;
  const uint16_t* Sgp = Sg_ + (size_t)blk*4096;
  const float* Pg = pkv + h*4096;
  #pragma unroll
  for (int v = 0; v < 2; ++v){
    int idx = (tid*2 + v)*8;
    int r = idx >> 6, cc = idx & 63;
    *(uint4*)&Kb[r*72 + cc] = *(const uint4*)&Kg[idx];
  }
  #pragma unroll
  for (int it = 0; it < 16; ++it){
    int idx = it*256 + tid;          // Vg: idx = s*64+d ; pkv: idx = d*64+e
    int r = idx >> 6, cc = idx & 63;
    VTb[cc*72 + r] = Vg[idx];        // VTb[d][s]
    B2[cc*72 + r] = f2bf(Pg[idx]);   // B2[e][d]
  }
  // direct global fragment loads (Q rows; S rows) — no LDS round-trip
  const int gfr = (w*16 + l16)*64 + quad*8;
  v8s aQ0 = *(const v8s*)&Qg[gfr], aQ1 = *(const v8s*)&Qg[gfr + 32];
  __syncthreads();
  const int ar = (w*16 + l16)*72 + quad*8;
  v4f accP[4] = {}, accPP[4] = {}, accIT[4] = {};
  #pragma unroll
  for (int ni = 0; ni < 4; ++ni){
    const int br = (ni*16 + l16)*72 + quad*8;
    const int gbr = (ni*16 + l16)*64 + quad*8;
    v8s b0 = *(v8s*)&Kb[br], b1 = *(v8s*)&Kb[br + 32];
    accP[ni] = __builtin_amdgcn_mfma_f32_16x16x32_bf16(aQ0, b0, accP[ni], 0, 0, 0);
    accP[ni] = __builtin_amdgcn_mfma_f32_16x16x32_bf16(aQ1, b1, accP[ni], 0, 0, 0);
    v8s c0 = *(v8s*)&B2[br], c1 = *(v8s*)&B2[br + 32];
    accPP[ni] = __builtin_amdgcn_mfma_f32_16x16x32_bf16(aQ0, c0, accPP[ni], 0, 0, 0);
    accPP[ni] = __builtin_amdgcn_mfma_f32_16x16x32_bf16(aQ1, c1, accPP[ni], 0, 0, 0);
    v8s d0 = *(const v8s*)&Sgp[gbr], d1 = *(const v8s*)&Sgp[gbr + 32];
    accIT[ni] = __builtin_amdgcn_mfma_f32_16x16x32_bf16(aQ0, d0, accIT[ni], 0, 0, 0);
    accIT[ni] = __builtin_amdgcn_mfma_f32_16x16x32_bf16(aQ1, d1, accIT[ni], 0, 0, 0);
  }
  __syncthreads();   // all reads of Kb/B2 complete
  #pragma unroll
  for (int ni = 0; ni < 4; ++ni){
    #pragma unroll
    for (int r = 0; r < 4; ++r){
      int i = w*16 + quad*4 + r;     // row (time)
      int j = ni*16 + l16;           // col
      Kb[i*72 + j] = f2bf((i >= j) ? accP[ni][r]*tab[i - j] : 0.0f);   // P'
      B2[j*72 + i] = f2bf(accPP[ni][r]);                               // ppT[e][i]
    }
  }
  __syncthreads();
  v8s aP0 = *(v8s*)&Kb[ar], aP1 = *(v8s*)&Kb[ar + 32];
  v8s aM0, aM1;
  {
    int i = w*16 + l16;
    #pragma unroll
    for (int u = 0; u < 8; ++u){
      int j0 = quad*8 + u, j1 = 32 + quad*8 + u;
      aM0[u] = (short)f2bf((j0 >= i) ? tab[j0 - i] : 0.0f);
      aM1[u] = (short)f2bf((j1 >= i) ? tab[j1 - i] : 0.0f);
    }
  }
  v4f accI[4] = {}, accX[4] = {};
  #pragma unroll
  for (int ni = 0; ni < 4; ++ni){
    const int br = (ni*16 + l16)*72 + quad*8;
    v8s b0 = *(v8s*)&VTb[br], b1 = *(v8s*)&VTb[br + 32];
    accI[ni] = __builtin_amdgcn_mfma_f32_16x16x32_bf16(aP0, b0, accI[ni], 0, 0, 0);
    accI[ni] = __builtin_amdgcn_mfma_f32_16x16x32_bf16(aP1, b1, accI[ni], 0, 0, 0);
    v8s e0 = *(v8s*)&B2[br], e1 = *(v8s*)&B2[br + 32];
    accX[ni] = __builtin_amdgcn_mfma_f32_16x16x32_bf16(aM0, e0, accX[ni], 0, 0, 0);
    accX[ni] = __builtin_amdgcn_mfma_f32_16x16x32_bf16(aM1, e1, accX[ni], 0, 0, 0);
  }
  const size_t rbase = (size_t)bh*2048 + (size_t)c*64;
  float s1 = 0.f, s2 = 0.f;
  #pragma unroll
  for (int ni = 0; ni < 4; ++ni){
    int d = ni*16 + l16;
    float tl = tailv[(size_t)blk*64 + d];
    #pragma unroll
    for (int r = 0; r < 4; ++r){
      int i = w*16 + quad*4 + r;
      float v = accI[ni][r] + tab[i + 1]*accIT[ni][r] + accX[ni][r] + tab[64 - i]*tl;
      ret[(rbase + i)*64 + d] = f2bf(v);
      s1 += v; s2 += v*v;
    }
  }
  #pragma unroll
  for (int off = 32; off > 0; off >>= 1){
    s1 += __shfl_down(s1, off);
    s2 += __shfl_down(s2, off);
  }
  if (lane == 0){ ps[w*2] = s1; ps[w*2+1] = s2; }
  __syncthreads();
  if (tid == 0){
    float2 o; o.x = ps[0] + ps[2] + ps[4] + ps[6];
    o.y = ps[1] + ps[3] + ps[5] + ps[7];
    pb[blk] = o;
  }
}

// reduce 512 per-block partials per batch -> stats
__global__ __launch_bounds__(256) void k_stats(const float2* __restrict__ pb, float* __restrict__ stats){
  __shared__ float ps[8];
  const int b = blockIdx.x;
  float s = 0.0f, s2 = 0.0f;
  for (int i = threadIdx.x; i < 512; i += 256){
    const float2 p = pb[(size_t)b*512 + i];
    s += p.x; s2 += p.y;
  }
  #pragma unroll
  for (int off = 32; off > 0; off >>= 1){
    s  += __shfl_down(s, off);
    s2 += __shfl_down(s2, off);
  }
  const int wv = threadIdx.x >> 6;
  if ((threadIdx.x & 63) == 0){ ps[wv*2] = s; ps[wv*2+1] = s2; }
  __syncthreads();
  if (threadIdx.x == 0){
    stats[b*2]   = ps[0] + ps[2] + ps[4] + ps[6];
    stats[b*2+1] = ps[1] + ps[3] + ps[5] + ps[7];
  }
}

// GroupNorm apply + layout to [B,T,NE]
__global__ __launch_bounds__(256) void k_norm(const uint16_t* __restrict__ ret, const float* __restrict__ stats,
                                              const float* __restrict__ gw, const float* __restrict__ gb,
                                              float* __restrict__ out){
  const int o = (blockIdx.x*256 + threadIdx.x)*4;
  const int b = o >> 21, t = (o >> 10) & 2047, cch = o & 1023;
  const int h = cch >> 6, d = cch & 63;
  const float inv = 1.0f/2097152.0f;
  const float mu = stats[b*2]*inv;
  const float var = stats[b*2+1]*inv - mu*mu;
  const float rs = rsqrtf(var + 1e-5f);
  const float w = gw[h]*rs, bb = gb[h];
  const ushort4 v = *(const ushort4*)&ret[((size_t)(b*16 + h)*2048 + t)*64 + d];
  float4 r;
  r.x = (bf2f(v.x) - mu)*w + bb; r.y = (bf2f(v.y) - mu)*w + bb;
  r.z = (bf2f(v.z) - mu)*w + bb; r.w = (bf2f(v.w) - mu)*w + bb;
  *(float4*)&out[o] = r;
}

extern "C" void kernel_launch(void* const* d_in, const int* in_sizes, int n_in,
                              void* d_out, int out_size, void* d_ws, size_t ws_size,
                              hipStream_t stream){
  const float* x   = (const float*)d_in[0];
  const float* pkv = (const float*)d_in[1];
  const float* Wq  = (const float*)d_in[2];
  const float* Wk  = (const float*)d_in[3];
  const float* Wv  = (const float*)d_in[4];
  const float* gnw = (const float*)d_in[5];
  const float* gnb = (const float*)d_in[6];
  float* out  = (float*)d_out;
  float* out2 = out + 8388608;

  char* ws = (char*)d_ws;
  size_t off = 0;
  float*    stats = (float*)(ws + off);    off += 256;
  float2*   pb    = (float2*)(ws + off);   off += (size_t)8192*8;
  uint16_t* Xb    = (uint16_t*)(ws + off); off += (size_t)8388608*2;
  uint16_t* Wt    = (uint16_t*)(ws + off); off += (size_t)3145728*2;
  uint16_t* QKV   = (uint16_t*)(ws + off); off += (size_t)3*8388608*2;
  uint16_t* ret   = (uint16_t*)(ws + off); off += (size_t)8388608*2;
  uint16_t* UT    = (uint16_t*)(ws + off); off += (size_t)8388608*2;
  uint16_t* S     = (uint16_t*)(ws + off); off += (size_t)8388608*2;
  uint16_t* CKp   = (uint16_t*)(ws + off); off += (size_t)8388608*2;
  float*    headv = (float*)(ws + off);    off += (size_t)131072*4;
  float*    tailv = (float*)(ws + off);    off += (size_t)131072*4;

  k_conv<<<8960, 256, 0, stream>>>(x, Wq, Wk, Wv, Xb, Wt);
  k_gemm<<<dim3(64, 24), 256, 0, stream>>>(Xb, Wt, QKV);
  k_pre<<<2048, 256, 0, stream>>>(QKV, pkv, UT, CKp, headv);
  k_scan<<<1104, 256, 0, stream>>>(UT, S, headv, tailv, pkv, CKp, out2);
  k_main<<<2048, 256, 0, stream>>>(QKV, S, pkv, tailv, ret, pb);
  k_stats<<<4, 256, 0, stream>>>(pb, stats);
  k_norm<<<8192, 256, 0, stream>>>(ret, stats, gnw, gnb, out);
}

// Round 7
// 233.238 us; speedup vs baseline: 1.3739x; 1.0004x over previous
//
#include <hip/hip_runtime.h>
#include <stdint.h>

typedef float v4f __attribute__((ext_vector_type(4)));
typedef short v8s __attribute__((ext_vector_type(8)));

#define SZ_BHTD 8388608   // B*H*T*DH
#define SZ_HTD  131072    // T*DH

#define GL2LDS(g, l) __builtin_amdgcn_global_load_lds( \
    (const __attribute__((address_space(1))) void*)(g), \
    (__attribute__((address_space(3))) void*)(l), 16, 0, 0)

__device__ __forceinline__ uint16_t f2bf(float f){
  uint32_t u = __float_as_uint(f);
  u += 0x7fffu + ((u >> 16) & 1u);
  return (uint16_t)(u >> 16);
}
__device__ __forceinline__ float bf2f(uint16_t v){
  return __uint_as_float(((uint32_t)v) << 16);
}

// Fused conversions: blocks [0,8192): x fp32->bf16; [8192,8960): W transpose->bf16;
// [8960,8976): pkv -> pkvT bf16 (per-head transpose, done ONCE instead of per
// k_main block).
__global__ __launch_bounds__(256) void k_conv(const float* __restrict__ x,
                                              const float* __restrict__ Wq, const float* __restrict__ Wk,
                                              const float* __restrict__ Wv, const float* __restrict__ pkv,
                                              uint16_t* __restrict__ xb, uint16_t* __restrict__ wt,
                                              uint16_t* __restrict__ pkvT){
  if (blockIdx.x < 8192){
    int i = blockIdx.x*256 + threadIdx.x;
    const float4 v = ((const float4*)x)[i];
    ushort4 o; o.x = f2bf(v.x); o.y = f2bf(v.y); o.z = f2bf(v.z); o.w = f2bf(v.w);
    ((ushort4*)xb)[i] = o;
    return;
  }
  __shared__ float t[64][65];
  if (blockIdx.x < 8960){
    const int blk2 = blockIdx.x - 8192;          // [0,768)
    const int z = blk2 >> 8, y = (blk2 >> 4) & 15, xx = blk2 & 15;
    const float* W = z==0 ? Wq : (z==1 ? Wk : Wv);
    int n0 = xx*64, k0 = y*64;
    for (int idx = threadIdx.x; idx < 4096; idx += 256){
      int r = idx >> 6, c = idx & 63;
      t[r][c] = W[(k0+r)*1024 + n0 + c];
    }
    __syncthreads();
    for (int idx = threadIdx.x; idx < 4096; idx += 256){
      int r = idx >> 6, c = idx & 63;   // r: local n, c: local k
      wt[(size_t)(z*1024 + n0 + r)*1024 + k0 + c] = f2bf(t[c][r]);
    }
    return;
  }
  const int h = blockIdx.x - 8960;               // [0,16)
  for (int idx = threadIdx.x; idx < 4096; idx += 256){
    int r = idx >> 6, c = idx & 63;              // r: d, c: e
    t[r][c] = pkv[h*4096 + r*64 + c];
  }
  __syncthreads();
  for (int idx = threadIdx.x; idx < 4096; idx += 256){
    int r = idx >> 6, c = idx & 63;              // r: e, c: d
    pkvT[h*4096 + r*64 + c] = f2bf(t[c][r]);     // pkvT[h][e][d]
  }
}

// QKV = Xb @ Wt^T. 128x128 tile, BK=64, global_load_lds width 16, XOR-swizzled LDS.
// m97-structure kernel, harness-verified ~64 us / 805 TF (its documented ceiling).
// 8-phase transplant abandoned after 3 structural failures (R1/R2/R4); do not retry.
__global__ __launch_bounds__(256) void k_gemm(const uint16_t* __restrict__ Xb, const uint16_t* __restrict__ Wt,
                                              uint16_t* __restrict__ qkv){
  __shared__ uint16_t As[128*64];
  __shared__ uint16_t Bs[128*64];
  const int tid = threadIdx.x;
  const int lane = tid & 63, w = tid >> 6;
  const int quad = lane >> 4, l16 = lane & 15;
  const int wm = (w >> 1)*64, wn = (w & 1)*64;
  const int bm = blockIdx.x, bn = blockIdx.y;
  v4f acc[4][4] = {};
  const uint16_t* Ag = Xb + (size_t)(bm*128)*1024;
  const uint16_t* Bg = Wt + (size_t)(bn*128)*1024;
  const int rA = lane >> 3;                     // 0..7 row within 8-row chunk
  const int ce = (((lane & 7) ^ rA) * 8);       // swizzled 16B column chunk (elements)
  const int xr = l16 & 7;                       // reader-side XOR key
  for (int k0 = 0; k0 < 1024; k0 += 64){
    #pragma unroll
    for (int j = 0; j < 4; ++j){
      const int cA = w*4 + j;                   // covers rows [cA*8, cA*8+8)
      const int r = cA*8 + rA;
      GL2LDS(Ag + (size_t)r*1024 + k0 + ce, As + cA*512);
      GL2LDS(Bg + (size_t)r*1024 + k0 + ce, Bs + cA*512);
    }
    __syncthreads();
    #pragma unroll
    for (int kk = 0; kk < 64; kk += 32){
      const int ch = ((quad + (kk >> 3)) ^ xr) * 8;   // kk=0 -> quad, kk=32 -> quad+4, then XOR
      v8s a[4], b[4];
      #pragma unroll
      for (int u = 0; u < 4; ++u) a[u] = *(v8s*)&As[(wm + u*16 + l16)*64 + ch];
      #pragma unroll
      for (int u = 0; u < 4; ++u) b[u] = *(v8s*)&Bs[(wn + u*16 + l16)*64 + ch];
      #pragma unroll
      for (int mi = 0; mi < 4; ++mi)
        #pragma unroll
        for (int ni = 0; ni < 4; ++ni)
          acc[mi][ni] = __builtin_amdgcn_mfma_f32_16x16x32_bf16(a[mi], b[ni], acc[mi][ni], 0, 0, 0);
    }
    __syncthreads();
  }
  #pragma unroll
  for (int mi = 0; mi < 4; ++mi){
    #pragma unroll
    for (int ni = 0; ni < 4; ++ni){
      int n = bn*128 + wn + ni*16 + l16;
      int which = n >> 10, cch = n & 1023;
      int hh = cch >> 6, dd = cch & 63;
      #pragma unroll
      for (int r = 0; r < 4; ++r){
        int m = bm*128 + wm + mi*16 + quad*4 + r;
        int b = m >> 11, t = m & 2047;
        qkv[(size_t)which*SZ_BHTD + (size_t)((b*16 + hh)*2048 + t)*64 + dd] = f2bf(acc[mi][ni][r]);
      }
    }
  }
}

// Per (b,h,chunk): UT[d][e]=sum_s g^{63-s}K[s][e]V[s][d]; CK[d][e]=sum_s K[s][d]V[s][e];
// head[e] = qbar . pkv with qbar[d]=sum_j g^j Q[j][d].
// VTw LDS array ELIMINATED: the g^{63-s} scaling is applied in-register on the
// VTb fragment (same op count, bit-identical) -> LDS 28.5 -> 19.5 KB.
__global__ __launch_bounds__(256) void k_pre(const uint16_t* __restrict__ qkv, const float* __restrict__ pkv,
                                             uint16_t* __restrict__ UT, uint16_t* __restrict__ ckp,
                                             float* __restrict__ headv){
  __shared__ uint16_t KTb[64*72];   // [d][s] = K[s][d]
  __shared__ uint16_t VTb[64*72];   // [e][s] = V[s][e]
  __shared__ float tab[65];
  __shared__ float qbar[64];
  __shared__ float part4[4][64];    // partial-reduce buffer (qbar, then headv)
  const int tid = threadIdx.x, blk = blockIdx.x;
  const int bh = blk >> 5, c = blk & 31, h = bh & 15;
  const int lane = tid & 63, w = tid >> 6;
  const int quad = lane >> 4, l16 = lane & 15;
  const float g = 1.0f - exp2f(-(float)(5 + h));
  if (tid <= 64) tab[tid] = powf(g, (float)tid);
  const uint16_t* Qg = qkv + (size_t)bh*SZ_HTD + c*4096;
  const uint16_t* Kg = Qg + SZ_BHTD;
  const uint16_t* Vg = Qg + 2*(size_t)SZ_BHTD;
  const float* Pg = pkv + h*4096;
  __syncthreads();
  #pragma unroll
  for (int it = 0; it < 16; ++it){
    int idx = it*256 + tid;            // idx = s*64 + d
    int s = idx >> 6, d = idx & 63;
    KTb[d*72 + s] = Kg[idx];
    VTb[d*72 + s] = Vg[idx];
  }
  {  // qbar partials: thread (w, lane) sums j in [w*16, w*16+16) for d=lane
    float acc = 0.f;
    #pragma unroll
    for (int jj = 0; jj < 16; ++jj){
      int j = w*16 + jj;
      acc = fmaf(tab[j], bf2f(Qg[j*64 + lane]), acc);
    }
    part4[w][lane] = acc;
  }
  __syncthreads();
  if (tid < 64) qbar[tid] = part4[0][tid] + part4[1][tid] + part4[2][tid] + part4[3][tid];
  const int ar = (w*16 + l16)*72 + quad*8;
  v8s aK0 = *(v8s*)&KTb[ar], aK1 = *(v8s*)&KTb[ar + 32];
  v8s aW0, aW1;
  {  // in-register g^{63-s} * V^T fragment (replaces the VTw LDS array)
    v8s vA0 = *(v8s*)&VTb[ar], vA1 = *(v8s*)&VTb[ar + 32];
    #pragma unroll
    for (int u = 0; u < 8; ++u){
      int s0 = quad*8 + u;
      aW0[u] = (short)f2bf(tab[63 - s0]*bf2f((uint16_t)vA0[u]));
      aW1[u] = (short)f2bf(tab[31 - s0]*bf2f((uint16_t)vA1[u]));
    }
  }
  v4f accC[4] = {}, accU[4] = {};
  #pragma unroll
  for (int ni = 0; ni < 4; ++ni){
    const int br = (ni*16 + l16)*72 + quad*8;
    v8s bV0 = *(v8s*)&VTb[br], bV1 = *(v8s*)&VTb[br + 32];
    v8s bK0 = *(v8s*)&KTb[br], bK1 = *(v8s*)&KTb[br + 32];
    accC[ni] = __builtin_amdgcn_mfma_f32_16x16x32_bf16(aK0, bV0, accC[ni], 0, 0, 0);
    accC[ni] = __builtin_amdgcn_mfma_f32_16x16x32_bf16(aK1, bV1, accC[ni], 0, 0, 0);
    accU[ni] = __builtin_amdgcn_mfma_f32_16x16x32_bf16(aW0, bK0, accU[ni], 0, 0, 0);
    accU[ni] = __builtin_amdgcn_mfma_f32_16x16x32_bf16(aW1, bK1, accU[ni], 0, 0, 0);
  }
  const size_t ob = (size_t)blk*4096;
  #pragma unroll
  for (int ni = 0; ni < 4; ++ni){
    int e = ni*16 + l16;
    #pragma unroll
    for (int r = 0; r < 4; ++r){
      int d = w*16 + quad*4 + r;
      ckp[ob + d*64 + e] = f2bf(accC[ni][r]);
      UT[ob + d*64 + e]  = f2bf(accU[ni][r]);
    }
  }
  __syncthreads();   // qbar visible to all; part4 free for reuse
  {  // headv partials: thread (w, lane) sums d in [w*16, w*16+16) for e=lane
    float acc = 0.f;
    #pragma unroll
    for (int dd = 0; dd < 16; ++dd){
      int d = w*16 + dd;
      acc = fmaf(qbar[d], Pg[d*64 + lane], acc);
    }
    part4[w][lane] = acc;
  }
  __syncthreads();
  if (tid < 64)
    headv[(size_t)blk*64 + tid] = part4[0][tid] + part4[1][tid] + part4[2][tid] + part4[3][tid];
}

// Merged scans + current_kv reduce.
// Blocks [0,1024): forward state scan S. [1024,1040): backward tail scan.
// [1040,1104): current_kv = gamma*past_kv + mean_b K^T V (overlaps the scan).
__global__ __launch_bounds__(256) void k_scan(const uint16_t* __restrict__ UT, uint16_t* __restrict__ S,
                                              const float* __restrict__ headv, float* __restrict__ tailv,
                                              const float* __restrict__ pkv, const uint16_t* __restrict__ ckp,
                                              float* __restrict__ out2){
  if (blockIdx.x < 1024){
    const int lin = blockIdx.x*256 + threadIdx.x;   // 262144 = 64 bh * 4096 elems
    const int bh = lin >> 12, off = lin & 4095, h = bh & 15;
    const float g = 1.0f - exp2f(-(float)(5 + h));
    const float g64 = powf(g, 64.0f);
    float st = 0.f;
    for (int c = 0; c < 32; ++c){
      const size_t base = ((size_t)(bh*32 + c))*4096 + off;
      uint16_t u = UT[base];
      S[base] = f2bf(st);
      st = fmaf(g64, st, bf2f(u));
    }
    return;
  }
  if (blockIdx.x < 1040){
    const int lin = (blockIdx.x - 1024)*256 + threadIdx.x;   // 4096 = B*H*DH
    const int bh = lin >> 6, e = lin & 63, h = bh & 15;
    const float g = 1.0f - exp2f(-(float)(5 + h));
    const float g64 = powf(g, 64.0f);
    float R = 0.0f;
    for (int c = 31; c >= 0; --c){
      const size_t o = ((size_t)bh*32 + c)*64 + e;
      tailv[o] = R;
      R = fmaf(g64, R, headv[o]);
    }
    return;
  }
  const int lin = (blockIdx.x - 1040)*256 + threadIdx.x;  // 16384
  const int i = lin*4;
  const int h = i >> 12, de = i & 4095;
  const float g = 1.0f - exp2f(-(float)(5 + h));
  float acc[4] = {0.0f, 0.0f, 0.0f, 0.0f};
  for (int b = 0; b < 4; ++b){
    const uint16_t* base = ckp + ((size_t)(b*16 + h)*32)*4096 + de;
    for (int c = 0; c < 32; ++c){
      #pragma unroll
      for (int u = 0; u < 4; ++u) acc[u] += bf2f(base[(size_t)c*4096 + u]);
    }
  }
  #pragma unroll
  for (int u = 0; u < 4; ++u)
    out2[i + u] = fmaf(g, pkv[i + u], 0.25f*acc[u]);
}

// Fused main: P=QK^T, pp=Q pkv^T, inter=Q S^T, intra=P' V, cx = M pp^T (all MFMA);
// ret (bf16) = intra + g^{i+1} inter + cx + g^{64-i} tail; partial GroupNorm stats.
// Q/S fragments read directly from global (R6 win). B2 initial staging now also
// eliminated: accPP's B-fragments come from the precomputed global pkvT
// (L2-resident); B2 is only the ppT scratch. Staging loop = VTb only.
__global__ __launch_bounds__(256) void k_main(const uint16_t* __restrict__ qkv, const uint16_t* __restrict__ Sg_,
                                              const uint16_t* __restrict__ pkvT, const float* __restrict__ tailv,
                                              uint16_t* __restrict__ ret, float2* __restrict__ pb){
  __shared__ uint16_t Kb[64*72];    // K rows [j][d] -> P' rows [i][s]
  __shared__ uint16_t VTb[64*72];   // [d][s] = V[s][d]
  __shared__ uint16_t B2[64*72];    // ppT [e][j] scratch
  __shared__ float tab[65];
  __shared__ float ps[8];
  const int tid = threadIdx.x, blk = blockIdx.x;
  const int bh = blk >> 5, c = blk & 31, h = bh & 15;
  const int lane = tid & 63, w = tid >> 6;
  const int quad = lane >> 4, l16 = lane & 15;
  const float g = 1.0f - exp2f(-(float)(5 + h));
  if (tid <= 64) tab[tid] = powf(g, (float)tid);
  const uint16_t* Qg = qkv + (size_t)bh*SZ_HTD + c*4096;
  const uint16_t* Kg = Qg + SZ_BHTD;
  const uint16_t* Vg = Qg + 2*(size_t)SZ_BHTD;
  const uint16_t* Sgp = Sg_ + (size_t)blk*4096;
  const uint16_t* PTg = pkvT + h*4096;
  #pragma unroll
  for (int v = 0; v < 2; ++v){
    int idx = (tid*2 + v)*8;
    int r = idx >> 6, cc = idx & 63;
    *(uint4*)&Kb[r*72 + cc] = *(const uint4*)&Kg[idx];
  }
  #pragma unroll
  for (int it = 0; it < 16; ++it){
    int idx = it*256 + tid;          // idx = s*64 + d
    int r = idx >> 6, cc = idx & 63;
    VTb[cc*72 + r] = Vg[idx];        // VTb[d][s]
  }
  // direct global fragment loads (Q rows) — no LDS round-trip
  const int gfr = (w*16 + l16)*64 + quad*8;
  v8s aQ0 = *(const v8s*)&Qg[gfr], aQ1 = *(const v8s*)&Qg[gfr + 32];
  __syncthreads();
  const int ar = (w*16 + l16)*72 + quad*8;
  v4f accP[4] = {}, accPP[4] = {}, accIT[4] = {};
  #pragma unroll
  for (int ni = 0; ni < 4; ++ni){
    const int br = (ni*16 + l16)*72 + quad*8;
    const int gbr = (ni*16 + l16)*64 + quad*8;
    v8s b0 = *(v8s*)&Kb[br], b1 = *(v8s*)&Kb[br + 32];
    accP[ni] = __builtin_amdgcn_mfma_f32_16x16x32_bf16(aQ0, b0, accP[ni], 0, 0, 0);
    accP[ni] = __builtin_amdgcn_mfma_f32_16x16x32_bf16(aQ1, b1, accP[ni], 0, 0, 0);
    v8s c0 = *(const v8s*)&PTg[gbr], c1 = *(const v8s*)&PTg[gbr + 32];
    accPP[ni] = __builtin_amdgcn_mfma_f32_16x16x32_bf16(aQ0, c0, accPP[ni], 0, 0, 0);
    accPP[ni] = __builtin_amdgcn_mfma_f32_16x16x32_bf16(aQ1, c1, accPP[ni], 0, 0, 0);
    v8s d0 = *(const v8s*)&Sgp[gbr], d1 = *(const v8s*)&Sgp[gbr + 32];
    accIT[ni] = __builtin_amdgcn_mfma_f32_16x16x32_bf16(aQ0, d0, accIT[ni], 0, 0, 0);
    accIT[ni] = __builtin_amdgcn_mfma_f32_16x16x32_bf16(aQ1, d1, accIT[ni], 0, 0, 0);
  }
  __syncthreads();   // all reads of Kb complete
  #pragma unroll
  for (int ni = 0; ni < 4; ++ni){
    #pragma unroll
    for (int r = 0; r < 4; ++r){
      int i = w*16 + quad*4 + r;     // row (time)
      int j = ni*16 + l16;           // col
      Kb[i*72 + j] = f2bf((i >= j) ? accP[ni][r]*tab[i - j] : 0.0f);   // P'
      B2[j*72 + i] = f2bf(accPP[ni][r]);                               // ppT[e][i]
    }
  }
  __syncthreads();
  v8s aP0 = *(v8s*)&Kb[ar], aP1 = *(v8s*)&Kb[ar + 32];
  v8s aM0, aM1;
  {
    int i = w*16 + l16;
    #pragma unroll
    for (int u = 0; u < 8; ++u){
      int j0 = quad*8 + u, j1 = 32 + quad*8 + u;
      aM0[u] = (short)f2bf((j0 >= i) ? tab[j0 - i] : 0.0f);
      aM1[u] = (short)f2bf((j1 >= i) ? tab[j1 - i] : 0.0f);
    }
  }
  v4f accI[4] = {}, accX[4] = {};
  #pragma unroll
  for (int ni = 0; ni < 4; ++ni){
    const int br = (ni*16 + l16)*72 + quad*8;
    v8s b0 = *(v8s*)&VTb[br], b1 = *(v8s*)&VTb[br + 32];
    accI[ni] = __builtin_amdgcn_mfma_f32_16x16x32_bf16(aP0, b0, accI[ni], 0, 0, 0);
    accI[ni] = __builtin_amdgcn_mfma_f32_16x16x32_bf16(aP1, b1, accI[ni], 0, 0, 0);
    v8s e0 = *(v8s*)&B2[br], e1 = *(v8s*)&B2[br + 32];
    accX[ni] = __builtin_amdgcn_mfma_f32_16x16x32_bf16(aM0, e0, accX[ni], 0, 0, 0);
    accX[ni] = __builtin_amdgcn_mfma_f32_16x16x32_bf16(aM1, e1, accX[ni], 0, 0, 0);
  }
  const size_t rbase = (size_t)bh*2048 + (size_t)c*64;
  float s1 = 0.f, s2 = 0.f;
  #pragma unroll
  for (int ni = 0; ni < 4; ++ni){
    int d = ni*16 + l16;
    float tl = tailv[(size_t)blk*64 + d];
    #pragma unroll
    for (int r = 0; r < 4; ++r){
      int i = w*16 + quad*4 + r;
      float v = accI[ni][r] + tab[i + 1]*accIT[ni][r] + accX[ni][r] + tab[64 - i]*tl;
      ret[(rbase + i)*64 + d] = f2bf(v);
      s1 += v; s2 += v*v;
    }
  }
  #pragma unroll
  for (int off = 32; off > 0; off >>= 1){
    s1 += __shfl_down(s1, off);
    s2 += __shfl_down(s2, off);
  }
  if (lane == 0){ ps[w*2] = s1; ps[w*2+1] = s2; }
  __syncthreads();
  if (tid == 0){
    float2 o; o.x = ps[0] + ps[2] + ps[4] + ps[6];
    o.y = ps[1] + ps[3] + ps[5] + ps[7];
    pb[blk] = o;
  }
}

// reduce 512 per-block partials per batch -> stats
__global__ __launch_bounds__(256) void k_stats(const float2* __restrict__ pb, float* __restrict__ stats){
  __shared__ float ps[8];
  const int b = blockIdx.x;
  float s = 0.0f, s2 = 0.0f;
  for (int i = threadIdx.x; i < 512; i += 256){
    const float2 p = pb[(size_t)b*512 + i];
    s += p.x; s2 += p.y;
  }
  #pragma unroll
  for (int off = 32; off > 0; off >>= 1){
    s  += __shfl_down(s, off);
    s2 += __shfl_down(s2, off);
  }
  const int wv = threadIdx.x >> 6;
  if ((threadIdx.x & 63) == 0){ ps[wv*2] = s; ps[wv*2+1] = s2; }
  __syncthreads();
  if (threadIdx.x == 0){
    stats[b*2]   = ps[0] + ps[2] + ps[4] + ps[6];
    stats[b*2+1] = ps[1] + ps[3] + ps[5] + ps[7];
  }
}

// GroupNorm apply + layout to [B,T,NE]
__global__ __launch_bounds__(256) void k_norm(const uint16_t* __restrict__ ret, const float* __restrict__ stats,
                                              const float* __restrict__ gw, const float* __restrict__ gb,
                                              float* __restrict__ out){
  const int o = (blockIdx.x*256 + threadIdx.x)*4;
  const int b = o >> 21, t = (o >> 10) & 2047, cch = o & 1023;
  const int h = cch >> 6, d = cch & 63;
  const float inv = 1.0f/2097152.0f;
  const float mu = stats[b*2]*inv;
  const float var = stats[b*2+1]*inv - mu*mu;
  const float rs = rsqrtf(var + 1e-5f);
  const float w = gw[h]*rs, bb = gb[h];
  const ushort4 v = *(const ushort4*)&ret[((size_t)(b*16 + h)*2048 + t)*64 + d];
  float4 r;
  r.x = (bf2f(v.x) - mu)*w + bb; r.y = (bf2f(v.y) - mu)*w + bb;
  r.z = (bf2f(v.z) - mu)*w + bb; r.w = (bf2f(v.w) - mu)*w + bb;
  *(float4*)&out[o] = r;
}

extern "C" void kernel_launch(void* const* d_in, const int* in_sizes, int n_in,
                              void* d_out, int out_size, void* d_ws, size_t ws_size,
                              hipStream_t stream){
  const float* x   = (const float*)d_in[0];
  const float* pkv = (const float*)d_in[1];
  const float* Wq  = (const float*)d_in[2];
  const float* Wk  = (const float*)d_in[3];
  const float* Wv  = (const float*)d_in[4];
  const float* gnw = (const float*)d_in[5];
  const float* gnb = (const float*)d_in[6];
  float* out  = (float*)d_out;
  float* out2 = out + 8388608;

  char* ws = (char*)d_ws;
  size_t off = 0;
  float*    stats = (float*)(ws + off);    off += 256;
  float2*   pb    = (float2*)(ws + off);   off += (size_t)8192*8;
  uint16_t* Xb    = (uint16_t*)(ws + off); off += (size_t)8388608*2;
  uint16_t* Wt    = (uint16_t*)(ws + off); off += (size_t)3145728*2;
  uint16_t* pkvT  = (uint16_t*)(ws + off); off += (size_t)65536*2;
  uint16_t* QKV   = (uint16_t*)(ws + off); off += (size_t)3*8388608*2;
  uint16_t* ret   = (uint16_t*)(ws + off); off += (size_t)8388608*2;
  uint16_t* UT    = (uint16_t*)(ws + off); off += (size_t)8388608*2;
  uint16_t* S     = (uint16_t*)(ws + off); off += (size_t)8388608*2;
  uint16_t* CKp   = (uint16_t*)(ws + off); off += (size_t)8388608*2;
  float*    headv = (float*)(ws + off);    off += (size_t)131072*4;
  float*    tailv = (float*)(ws + off);    off += (size_t)131072*4;

  k_conv<<<8976, 256, 0, stream>>>(x, Wq, Wk, Wv, pkv, Xb, Wt, pkvT);
  k_gemm<<<dim3(64, 24), 256, 0, stream>>>(Xb, Wt, QKV);
  k_pre<<<2048, 256, 0, stream>>>(QKV, pkv, UT, CKp, headv);
  k_scan<<<1104, 256, 0, stream>>>(UT, S, headv, tailv, pkv, CKp, out2);
  k_main<<<2048, 256, 0, stream>>>(QKV, S, pkvT, tailv, ret, pb);
  k_stats<<<4, 256, 0, stream>>>(pb, stats);
  k_norm<<<8192, 256, 0, stream>>>(ret, stats, gnw, gnb, out);
}